// Round 6
// baseline (6436.032 us; speedup 1.0000x reference)
//
#include <hip/hip_runtime.h>
#include <math.h>

// SE3Net forward, fp32.
//   blurZ,blurY(x) -> conv1(5^3,p4,+fused x-blur) -> gated
//   -> blurZ,blurY(expand) -> conv2(5^3,s2,p2,+fused x-blur) -> gated
//   -> blurZ,blurY,blurX(expand) -> conv3(5^3,s2,p2, split-K=2) -> gated(sum)
//   -> conv4(5^3,p4, split-K=4) -> relu+avg(sum) -> linear
// Identity: conv(pad4,s1) is a FULL conv, so downsample(G*(W*x)) ==
// downsample(W*(G_exp*x)) with G_exp on its full support (D->D+4).
// convK: double-buffered LDS, register-prefetch staging, 1 barrier per ci.

struct GaussW { float g[5]; };
#define B_ 16

// ---------------- separable 1D blur pass along z (AXIS=2) or y (AXIS=1) ----
template<int NBC, int DZ, int DY, int DX, int AXIS, int EXP>
__global__ __launch_bounds__(256) void blur1d(
    const float* __restrict__ in, float* __restrict__ out, GaussW gw)
{
  constexpr int DZO = DZ + ((AXIS == 2 && EXP) ? 4 : 0);
  constexpr int DYO = DY + ((AXIS == 1 && EXP) ? 4 : 0);
  constexpr int OFF = EXP ? 4 : 2;
  constexpr int NV  = DX / 4;
  constexpr int TOT = NBC * DZO * DYO * NV;
  int idx = blockIdx.x * 256 + threadIdx.x;
  if (idx >= TOT) return;
  int xv = idx % NV;
  int t  = idx / NV;
  int y  = t % DYO;
  t /= DYO;
  int z  = t % DZO;
  int bc = t / DZO;
  const float* p = in + (size_t)bc * DZ * DY * DX;
  float4 s = make_float4(0.f, 0.f, 0.f, 0.f);
  #pragma unroll
  for (int k = 0; k < 5; ++k) {
    int c = (AXIS == 2 ? z : y) + k - OFF;
    if (c < 0 || c >= (AXIS == 2 ? DZ : DY)) continue;
    const float4 v = *(const float4*)(p +
        (AXIS == 2 ? ((size_t)c * DY + y) : ((size_t)z * DY + c)) * DX + 4 * xv);
    float g = gw.g[k];
    s.x = fmaf(g, v.x, s.x);
    s.y = fmaf(g, v.y, s.y);
    s.z = fmaf(g, v.z, s.z);
    s.w = fmaf(g, v.w, s.w);
  }
  *(float4*)(out + (((size_t)bc * DZO + z) * DYO + y) * DX + 4 * xv) = s;
}

// ---------------- x-axis expanding blur: (DZ,DY,DXI) -> (DZ,DY,DXI+4) ------
template<int NBC, int DZ, int DY, int DXI>
__global__ __launch_bounds__(256) void blur1dx(
    const float* __restrict__ in, float* __restrict__ out, GaussW gw)
{
  constexpr int DXO = DXI + 4;
  static_assert(DXO % 4 == 0, "DXO must be /4");
  constexpr int NV  = DXO / 4;
  constexpr int TOT = NBC * DZ * DY * NV;
  int idx = blockIdx.x * 256 + threadIdx.x;
  if (idx >= TOT) return;
  int xv = idx % NV;
  int t  = idx / NV;
  int y  = t % DY;
  t /= DY;
  int z  = t % DZ;
  int bc = t / DZ;
  const float* row = in + ((size_t)bc * DZ + z) * DY * DXI + (size_t)y * DXI;
  float win[12];
  #pragma unroll
  for (int q = 0; q < 12; ++q) {
    int gx = 4 * xv + q - 4;
    win[q] = (gx >= 0 && gx < DXI) ? row[gx] : 0.f;
  }
  float o[4];
  #pragma unroll
  for (int q = 0; q < 4; ++q) {
    float s = 0.f;
    #pragma unroll
    for (int k = 0; k < 5; ++k) s = fmaf(gw.g[k], win[q + k], s);
    o[q] = s;
  }
  *(float4*)(out + (((size_t)bc * DZ + z) * DY + y) * DXO + 4 * xv) =
      make_float4(o[0], o[1], o[2], o[3]);
}

// ---------------- weight transpose: W[co][ci][125] -> Wt[ci][k][COP], pad 0 --
template<int CIN, int COUT, int COP>
__global__ __launch_bounds__(256) void k_transpose_w(
    const float* __restrict__ W, float* __restrict__ Wt)
{
  constexpr int TOT = CIN * 125 * COP;
  int idx = blockIdx.x * 256 + threadIdx.x;
  if (idx >= TOT) return;
  int co = idx % COP;
  int k  = (idx / COP) % 125;
  int ci = idx / (COP * 125);
  Wt[idx] = (co < COUT) ? W[((size_t)co * CIN + ci) * 125 + k] : 0.f;
}

// ---------------- tiled direct 5^3 conv, double-buffered -------------------
// in: [B][CIN][DIN(z)][DIN(y)][XSRC(x)] (XSRC<DIN when FUSEX).
// wt: [CIN][125][COP]. out: [B][COUT][DOUT^3] (+ split_stride per blockIdx.z).
// Per ci: prefetch ci+1 to regs during compute(ci); ds_write + ONE barrier.
template<int S, int CIN, int CSPLIT, int COUT, int COP, int COB, int NCB,
         int DIN, int XSRC, int DOUT, int PAD, int ZT, int YT, int XB,
         int SPTP, int FUSEX, int XOFF>
__global__ __launch_bounds__(256)
void convK(const float* __restrict__ in, const float* __restrict__ wt,
           float* __restrict__ out, size_t split_stride, GaussW gw)
{
  constexpr int K = 5;
  static_assert(DOUT % XB == 0, "XB must divide DOUT");
  constexpr int XQ  = DOUT / XB;
  constexpr int SPT = ZT * YT * XQ;
  static_assert(SPT <= SPTP, "SPTP too small");
  constexpr int NTH = SPTP * NCB;
  static_assert(NTH == 256, "block size 256");
  constexpr int XIN = (DOUT - 1) * S + K;
  constexpr int YIN = (YT - 1) * S + K;
  constexpr int ZIN = (ZT - 1) * S + K;
  constexpr int HXP = (S == 2) ? ((DOUT + 2 + 3) & ~3) : 0;
  constexpr int RW0 = (S == 2) ? (2 * HXP) : ((XIN + 3) & ~3);
  constexpr int RW  = (RW0 % 32 == 0 || RW0 % 32 == 16) ? (RW0 + 4) : RW0;
  constexpr int NROW = ZIN * YIN;
  constexpr int NIN  = NROW * RW;
  static_assert(DOUT % ZT == 0, "ZT must divide DOUT");
  constexpr int NZT = DOUT / ZT;
  constexpr int NYT = (DOUT + YT - 1) / YT;
  constexpr int D2  = DOUT * DOUT;
  constexpr int CI_PER = CIN / CSPLIT;
  constexpr int SLOTS = (NIN + NTH - 1) / NTH;

  __shared__ __align__(16) float s_in[2][NIN];

  const int tid = threadIdx.x;
  const int cbg = __builtin_amdgcn_readfirstlane(tid / SPTP);  // wave-uniform
  const int sp  = tid % SPTP;

  const int bxi = blockIdx.x;
  const int yt  = bxi % NYT;
  const int zt  = (bxi / NYT) % NZT;
  const int b   = bxi / (NYT * NZT);
  const int cb  = blockIdx.y;
  const int spl = blockIdx.z;
  const int co0 = cb * (COB * NCB) + cbg * COB;
  const int oz0 = zt * ZT;
  const int oy0 = yt * YT;
  const int ci0 = spl * CI_PER;

  bool act = sp < SPT;
  int txq = act ? sp % XQ : 0;
  int t2  = act ? sp / XQ : 0;
  int tyl = t2 % YT;
  int tzl = t2 / YT;
  act = act && (oy0 + tyl < DOUT);
  if (!act) { txq = 0; tyl = 0; tzl = 0; }

  float acc[XB][COB];
  #pragma unroll
  for (int j = 0; j < XB; ++j)
    #pragma unroll
    for (int c = 0; c < COB; ++c) acc[j][c] = 0.f;

  // ---- staging value for slot s of channel ci (identical math to r4) ----
  auto stage_val = [&](int s, int ci) -> float {
    int i = tid + s * NTH;
    float v = 0.f;
    if (i < NIN) {
      int row = i / RW;
      int wx  = i - row * RW;
      int sz = row / YIN;
      int sy = row - sz * YIN;
      int u;
      if (S == 2) u = (wx < HXP) ? (2 * wx) : (wx < 2 * HXP ? 2 * (wx - HXP) + 1 : -1);
      else        u = (wx < XIN) ? wx : -1;
      int gz = oz0 * S + sz - PAD;
      int gy = oy0 * S + sy - PAD;
      int gx = u - PAD;
      if (u >= 0 && gz >= 0 && gz < DIN && gy >= 0 && gy < DIN &&
          gx >= 0 && gx < DIN) {
        const float* src = in +
            (((size_t)b * CIN + ci) * DIN + gz) * ((size_t)DIN * XSRC) +
            (size_t)gy * XSRC;
        if constexpr (FUSEX) {
          float sacc = 0.f;
          #pragma unroll
          for (int tp = 0; tp < 5; ++tp) {
            int xs = gx + tp - XOFF;
            if (xs >= 0 && xs < XSRC) sacc = fmaf(gw.g[tp], src[xs], sacc);
          }
          v = sacc;
        } else {
          v = src[gx];
        }
      }
    }
    return v;
  };

  // ---- compute for channel ci from LDS buffer sbuf ----
  auto compute_ci = [&](const float* sbuf, int ci) {
    const float* wci = wt + (size_t)ci * 125 * COP + co0;  // wave-uniform
    #pragma unroll 1
    for (int kz = 0; kz < K; ++kz) {
      #pragma unroll 1
      for (int ky = 0; ky < K; ++ky) {
        const float* rp = &sbuf[((tzl * S + kz) * YIN + (tyl * S + ky)) * RW];
        float fe[8], fo[8];
        if constexpr (S == 2) {
          const float* ep = rp + XB * txq;
          const float* op = rp + HXP + XB * txq;
          if constexpr ((XB & 3) == 0) {
            float4 a = *(const float4*)ep, b4 = *(const float4*)(ep + 4);
            fe[0]=a.x; fe[1]=a.y; fe[2]=a.z; fe[3]=a.w;
            fe[4]=b4.x; fe[5]=b4.y; fe[6]=b4.z; fe[7]=b4.w;
            float4 c4 = *(const float4*)op, d4 = *(const float4*)(op + 4);
            fo[0]=c4.x; fo[1]=c4.y; fo[2]=c4.z; fo[3]=c4.w;
            fo[4]=d4.x; fo[5]=d4.y; fo[6]=d4.z; fo[7]=d4.w;
          } else if constexpr ((XB & 1) == 0) {
            #pragma unroll
            for (int q = 0; q < 4; ++q) {
              float2 a = *(const float2*)(ep + 2 * q);
              fe[2*q] = a.x; fe[2*q+1] = a.y;
              float2 b2 = *(const float2*)(op + 2 * q);
              fo[2*q] = b2.x; fo[2*q+1] = b2.y;
            }
          } else {
            #pragma unroll
            for (int q = 0; q < XB + 2; ++q) { fe[q] = ep[q]; fo[q] = op[q]; }
            #pragma unroll
            for (int q = XB + 2; q < 8; ++q) { fe[q] = 0.f; fo[q] = 0.f; }
          }
        } else {
          const float* wp0 = rp + XB * txq;
          float4 a = *(const float4*)wp0, b4 = *(const float4*)(wp0 + 4);
          fe[0]=a.x; fe[1]=a.y; fe[2]=a.z; fe[3]=a.w;
          fe[4]=b4.x; fe[5]=b4.y; fe[6]=b4.z; fe[7]=b4.w;
          fo[0]=0.f; fo[1]=0.f; fo[2]=0.f; fo[3]=0.f;
          fo[4]=0.f; fo[5]=0.f; fo[6]=0.f; fo[7]=0.f;
        }
        const float* wk = wci + (kz * 25 + ky * 5) * COP;
        #pragma unroll
        for (int kx = 0; kx < K; ++kx) {
          const float* wp = wk + kx * COP;
          float wv[COB];
          #pragma unroll
          for (int c = 0; c < COB; ++c) wv[c] = wp[c];  // scalar loads
          #pragma unroll
          for (int j = 0; j < XB; ++j) {
            float iv;
            if constexpr (S == 2)
              iv = (kx & 1) ? fo[j + (kx >> 1)] : fe[j + (kx >> 1)];
            else
              iv = fe[j + kx];
            #pragma unroll
            for (int c = 0; c < COB; ++c)
              acc[j][c] = fmaf(iv, wv[c], acc[j][c]);
          }
        }
      }
    }
  };

  // ---- main loop: dbuf LDS, reg-prefetch, 1 barrier/ci ----
  float pf[SLOTS];
  #pragma unroll
  for (int s = 0; s < SLOTS; ++s) pf[s] = stage_val(s, ci0);
  #pragma unroll
  for (int s = 0; s < SLOTS; ++s) {
    int i = tid + s * NTH;
    if (i < NIN) s_in[0][i] = pf[s];
  }
  __syncthreads();
  int cur = 0;
  #pragma unroll 1
  for (int r = 0; r < CI_PER; ++r) {
    if (r + 1 < CI_PER) {
      #pragma unroll
      for (int s = 0; s < SLOTS; ++s) pf[s] = stage_val(s, ci0 + r + 1);
    }
    compute_ci(&s_in[cur][0], ci0 + r);
    if (r + 1 < CI_PER) {
      #pragma unroll
      for (int s = 0; s < SLOTS; ++s) {
        int i = tid + s * NTH;
        if (i < NIN) s_in[cur ^ 1][i] = pf[s];
      }
      __syncthreads();
      cur ^= 1;
    }
  }

  // ---- store ----
  if (act) {
    const int oz = oz0 + tzl, oy = oy0 + tyl, ox = txq * XB;
    float* ob = out + (size_t)spl * split_stride;
    #pragma unroll
    for (int c = 0; c < COB; ++c) {
      int co = co0 + c;
      if (co < COUT) {
        float* p = ob + (((size_t)b * COUT + co) * DOUT + oz) * D2 +
                   (size_t)oy * DOUT + ox;
        if constexpr ((XB & 3) == 0) {
          #pragma unroll
          for (int q = 0; q < XB / 4; ++q)
            *(float4*)(p + 4 * q) = make_float4(acc[4*q][c], acc[4*q+1][c],
                                                acc[4*q+2][c], acc[4*q+3][c]);
        } else if constexpr ((XB & 1) == 0) {
          #pragma unroll
          for (int q = 0; q < XB / 2; ++q)
            *(float2*)(p + 2 * q) = make_float2(acc[2*q][c], acc[2*q+1][c]);
        } else {
          #pragma unroll
          for (int j = 0; j < XB; ++j) p[j] = acc[j][c];
        }
      }
    }
  }
}

// ---------------- gated nonlinearity (float4, optional split-K sum) --------
__global__ __launch_bounds__(256) void k_gated4(
    const float* __restrict__ in, const float* __restrict__ in2,
    float* __restrict__ out, int S3v, int Cin, int n_scalar, int n_gate,
    int m1, int d1, int m2, int d2, int m3, int d3, int n_out)
{
  int idx = blockIdx.x * 256 + threadIdx.x;
  int oc = blockIdx.y;
  int b  = blockIdx.z;
  if (idx >= S3v) return;
  size_t S3 = (size_t)S3v * 4;
  auto ld = [&](int ch) {
    size_t o = ((size_t)b * Cin + ch) * S3 + 4 * (size_t)idx;
    float4 v = *(const float4*)(in + o);
    if (in2) {
      float4 w = *(const float4*)(in2 + o);
      v.x += w.x; v.y += w.y; v.z += w.z; v.w += w.w;
    }
    return v;
  };
  float4 val;
  if (oc < n_scalar) {
    float4 v = ld(oc);
    val = make_float4(fmaxf(v.x, 0.f), fmaxf(v.y, 0.f),
                      fmaxf(v.z, 0.f), fmaxf(v.w, 0.f));
  } else {
    int o = oc - n_scalar;
    int gate_ch;
    if (o < m1 * d1) gate_ch = n_scalar + o / d1;
    else if (o - m1 * d1 < m2 * d2) gate_ch = n_scalar + m1 + (o - m1 * d1) / d2;
    else gate_ch = n_scalar + m1 + m2 + (o - m1 * d1 - m2 * d2) / d3;
    float4 v = ld(n_scalar + n_gate + o);
    float4 g = ld(gate_ch);
    val = make_float4(v.x / (1.f + expf(-g.x)), v.y / (1.f + expf(-g.y)),
                      v.z / (1.f + expf(-g.z)), v.w / (1.f + expf(-g.w)));
  }
  *(float4*)(out + ((size_t)b * n_out + oc) * S3 + 4 * (size_t)idx) = val;
}

// ---------------- sum splits + relu + spatial mean -------------------------
__global__ __launch_bounds__(256) void k_relu_avg(
    const float* __restrict__ in, float* __restrict__ h, int nspl,
    size_t sstride)
{
  int bc = blockIdx.x;               // b*64 + c
  const float* p = in + (size_t)bc * 4096;
  float s = 0.f;
  for (int i = threadIdx.x; i < 1024; i += 256) {
    float4 v = *(const float4*)(p + 4 * i);
    for (int k = 1; k < nspl; ++k) {
      float4 w = *(const float4*)(p + (size_t)k * sstride + 4 * i);
      v.x += w.x; v.y += w.y; v.z += w.z; v.w += w.w;
    }
    s += fmaxf(v.x, 0.f) + fmaxf(v.y, 0.f) + fmaxf(v.z, 0.f) + fmaxf(v.w, 0.f);
  }
  #pragma unroll
  for (int off = 32; off > 0; off >>= 1) s += __shfl_down(s, off, 64);
  __shared__ float wsum[4];
  int wid = threadIdx.x >> 6;
  if ((threadIdx.x & 63) == 0) wsum[wid] = s;
  __syncthreads();
  if (threadIdx.x == 0)
    h[bc] = (wsum[0] + wsum[1] + wsum[2] + wsum[3]) * (1.f / 4096.f);
}

// ---------------- final linear [16,64] @ [10,64]^T + b ---------------------
__global__ __launch_bounds__(256) void k_linear(
    const float* __restrict__ h, const float* __restrict__ Wl,
    const float* __restrict__ bl, float* __restrict__ out)
{
  int t = threadIdx.x;
  if (t >= 160) return;
  int b = t / 10, o = t - b * 10;
  const float* hp = h + b * 64;
  const float* wp = Wl + o * 64;
  float s = bl[o];
  #pragma unroll
  for (int c = 0; c < 64; ++c) s = fmaf(hp[c], wp[c], s);
  out[t] = s;
}

extern "C" void kernel_launch(void* const* d_in, const int* in_sizes, int n_in,
                              void* d_out, int out_size, void* d_ws, size_t ws_size,
                              hipStream_t stream)
{
  const float* x  = (const float*)d_in[0];
  const float* W1 = (const float*)d_in[1];
  const float* W2 = (const float*)d_in[2];
  const float* W3 = (const float*)d_in[3];
  const float* W4 = (const float*)d_in[4];
  const float* Wl = (const float*)d_in[5];
  const float* bl = (const float*)d_in[6];
  float* out = (float*)d_out;
  float* ws  = (float*)d_ws;

  // gaussian taps (scale=2): sigma=0.5*sqrt(3), size 5, normalized
  GaussW gw;
  {
    double gv[5], sum = 0.0;
    for (int i = 0; i < 5; ++i) { double r = i - 2; gv[i] = exp(-r * r / 1.5); sum += gv[i]; }
    for (int i = 0; i < 5; ++i) gw.g[i] = (float)(gv[i] / sum);
  }

  // workspace (floats), 64-aligned chunks; same total as verified round 4.
  size_t off = 0;
  auto A = [&](size_t n) { size_t o = off; off += (n + 63) & ~(size_t)63; return o; };
  size_t o_lp  = A(524288);              // z,y-blurred input 16x1x32^3
  size_t o_W1t = A(4000);                // [1][125][32]
  size_t o_W2t = A(300000);              // [25][125][96]
  size_t o_W3t = A(864000);              // [72][125][96]
  size_t o_W4t = A(640000);              // [80][125][64]
  size_t o_h   = A(1024);
  size_t o_A   = A(23040000);            // ping region A
  size_t o_B   = A(22394880);            // ping region B
  if (ws_size < off * sizeof(float)) return;

  float* lp  = ws + o_lp;
  float* W1t = ws + o_W1t;
  float* W2t = ws + o_W2t;
  float* W3t = ws + o_W3t;
  float* W4t = ws + o_W4t;
  float* hb  = ws + o_h;
  float* Ab  = ws + o_A;
  float* Bb  = ws + o_B;

  // weight prep
  k_transpose_w<1, 30, 32><<<16, 256, 0, stream>>>(W1, W1t);
  k_transpose_w<25, 88, 96><<<(300000 + 255) / 256, 256, 0, stream>>>(W2, W2t);
  k_transpose_w<72, 96, 96><<<(864000 + 255) / 256, 256, 0, stream>>>(W3, W3t);
  k_transpose_w<80, 64, 64><<<(640000 + 255) / 256, 256, 0, stream>>>(W4, W4t);

  // input blur (crop): z pass x->A, y pass A->lp; x pass fused into conv1
  blur1d<16, 32, 32, 32, 2, 0><<<(16 * 32 * 32 * 8 + 255) / 256, 256, 0, stream>>>(x, Ab, gw);
  blur1d<16, 32, 32, 32, 1, 0><<<(16 * 32 * 32 * 8 + 255) / 256, 256, 0, stream>>>(Ab, lp, gw);

  // conv1: lp(1, 32^3 virtual, fused x crop-blur) -> B (30, 36^3)
  convK<1, 1, 1, 30, 32, 8, 2, 32, 32, 36, 4, 2, 7, 4, 128, 1, 2>
      <<<dim3(16 * 18 * 6, 2, 1), 256, 0, stream>>>(lp, W1t, Bb, 0, gw);
  // gated1 -> A (25, 36^3)
  k_gated4<<<dim3(46, 25, 16), 256, 0, stream>>>(Bb, nullptr, Ab, 11664, 30, 2, 5,
                                                 2, 3, 2, 5, 1, 7, 25);
  // blur2 (expand): z A->B (40,36,36), y B->A (40,40,36)
  blur1d<400, 36, 36, 36, 2, 1><<<(400 * 40 * 36 * 9 + 255) / 256, 256, 0, stream>>>(Ab, Bb, gw);
  blur1d<400, 40, 36, 36, 1, 1><<<(400 * 40 * 40 * 9 + 255) / 256, 256, 0, stream>>>(Bb, Ab, gw);
  // conv2: A(25, 40^3 virtual, x from 36) -> B (88, 20^3)
  convK<2, 25, 1, 88, 96, 8, 4, 40, 36, 20, 2, 2, 6, 4, 64, 1, 4>
      <<<dim3(640, 3, 1), 256, 0, stream>>>(Ab, W2t, Bb, 0, gw);
  // gated2 -> A (72, 20^3)
  k_gated4<<<dim3(8, 72, 16), 256, 0, stream>>>(Bb, nullptr, Ab, 2000, 88, 8, 16,
                                                8, 3, 8, 5, 0, 1, 72);
  // blur3 (expand): z A->B (24,20,20), y B->A (24,24,20), x A->B (24,24,24)
  blur1d<1152, 20, 20, 20, 2, 1><<<(1152 * 24 * 20 * 5 + 255) / 256, 256, 0, stream>>>(Ab, Bb, gw);
  blur1d<1152, 24, 20, 20, 1, 1><<<(1152 * 24 * 24 * 5 + 255) / 256, 256, 0, stream>>>(Bb, Ab, gw);
  blur1dx<1152, 24, 24, 20><<<(1152 * 24 * 24 * 6 + 255) / 256, 256, 0, stream>>>(Ab, Bb, gw);
  // conv3: B(72, 24^3) -> A: P0, P1 (each 96, 12^3), split-K=2
  convK<2, 72, 2, 96, 96, 8, 4, 24, 24, 12, 2, 4, 4, 3, 64, 0, 0>
      <<<dim3(144, 3, 2), 256, 0, stream>>>(Bb, W3t, Ab, 2654208, gw);
  // gated3 (sum splits) -> B (80, 12^3)
  k_gated4<<<dim3(2, 80, 16), 256, 0, stream>>>(Ab, Ab + 2654208, Bb, 432, 96, 16, 16,
                                                8, 3, 8, 5, 0, 1, 80);
  // conv4: B(80, 12^3) -> A: P0..P3 (each 64, 16^3), split-K=4
  convK<1, 80, 4, 64, 64, 8, 4, 12, 12, 16, 4, 2, 8, 4, 64, 0, 0>
      <<<dim3(256, 2, 4), 256, 0, stream>>>(Bb, W4t, Ab, 4194304, gw);
  // sum splits + relu + spatial mean -> hb[16*64]
  k_relu_avg<<<1024, 256, 0, stream>>>(Ab, hb, 4, 4194304);
  // linear -> out[16*10]
  k_linear<<<1, 256, 0, stream>>>(hb, Wl, bl, out);
}

// Round 7
// 3650.653 us; speedup vs baseline: 1.7630x; 1.7630x over previous
//
#include <hip/hip_runtime.h>
#include <math.h>

// SE3Net forward, fp32.
//   blurZ,blurY(x) -> conv1(5^3,p4,+fused x-blur) -> gated
//   -> blurZ,blurY(expand) -> conv2(5^3,s2,p2,+fused x-blur) -> gated
//   -> blurZ,blurY,blurX(expand) -> conv3(5^3,s2,p2, split-K=2) -> gated(sum)
//   -> conv4(5^3,p4, split-K=4) -> relu+avg(sum) -> linear
// Identity: conv(pad4,s1) is a FULL conv, so downsample(G*(W*x)) ==
// downsample(W*(G_exp*x)) with G_exp on its full support (D->D+4).
// convK: round-4 verified structure (single LDS buffer, stage->bar->compute->bar
// per CIB channels). Round-6's reg-prefetch dbuf regressed (VGPR 136, occ 10.6%).

struct GaussW { float g[5]; };
#define B_ 16

// ---------------- separable 1D blur pass along z (AXIS=2) or y (AXIS=1) ----
template<int NBC, int DZ, int DY, int DX, int AXIS, int EXP>
__global__ __launch_bounds__(256) void blur1d(
    const float* __restrict__ in, float* __restrict__ out, GaussW gw)
{
  constexpr int DZO = DZ + ((AXIS == 2 && EXP) ? 4 : 0);
  constexpr int DYO = DY + ((AXIS == 1 && EXP) ? 4 : 0);
  constexpr int OFF = EXP ? 4 : 2;
  constexpr int NV  = DX / 4;
  constexpr int TOT = NBC * DZO * DYO * NV;
  int idx = blockIdx.x * 256 + threadIdx.x;
  if (idx >= TOT) return;
  int xv = idx % NV;
  int t  = idx / NV;
  int y  = t % DYO;
  t /= DYO;
  int z  = t % DZO;
  int bc = t / DZO;
  const float* p = in + (size_t)bc * DZ * DY * DX;
  float4 s = make_float4(0.f, 0.f, 0.f, 0.f);
  #pragma unroll
  for (int k = 0; k < 5; ++k) {
    int c = (AXIS == 2 ? z : y) + k - OFF;
    if (c < 0 || c >= (AXIS == 2 ? DZ : DY)) continue;
    const float4 v = *(const float4*)(p +
        (AXIS == 2 ? ((size_t)c * DY + y) : ((size_t)z * DY + c)) * DX + 4 * xv);
    float g = gw.g[k];
    s.x = fmaf(g, v.x, s.x);
    s.y = fmaf(g, v.y, s.y);
    s.z = fmaf(g, v.z, s.z);
    s.w = fmaf(g, v.w, s.w);
  }
  *(float4*)(out + (((size_t)bc * DZO + z) * DYO + y) * DX + 4 * xv) = s;
}

// ---------------- x-axis expanding blur: (DZ,DY,DXI) -> (DZ,DY,DXI+4) ------
template<int NBC, int DZ, int DY, int DXI>
__global__ __launch_bounds__(256) void blur1dx(
    const float* __restrict__ in, float* __restrict__ out, GaussW gw)
{
  constexpr int DXO = DXI + 4;
  static_assert(DXO % 4 == 0, "DXO must be /4");
  constexpr int NV  = DXO / 4;
  constexpr int TOT = NBC * DZ * DY * NV;
  int idx = blockIdx.x * 256 + threadIdx.x;
  if (idx >= TOT) return;
  int xv = idx % NV;
  int t  = idx / NV;
  int y  = t % DY;
  t /= DY;
  int z  = t % DZ;
  int bc = t / DZ;
  const float* row = in + ((size_t)bc * DZ + z) * DY * DXI + (size_t)y * DXI;
  float win[12];
  #pragma unroll
  for (int q = 0; q < 12; ++q) {
    int gx = 4 * xv + q - 4;
    win[q] = (gx >= 0 && gx < DXI) ? row[gx] : 0.f;
  }
  float o[4];
  #pragma unroll
  for (int q = 0; q < 4; ++q) {
    float s = 0.f;
    #pragma unroll
    for (int k = 0; k < 5; ++k) s = fmaf(gw.g[k], win[q + k], s);
    o[q] = s;
  }
  *(float4*)(out + (((size_t)bc * DZ + z) * DY + y) * DXO + 4 * xv) =
      make_float4(o[0], o[1], o[2], o[3]);
}

// ---------------- weight transpose: W[co][ci][125] -> Wt[ci][k][COP], pad 0 --
template<int CIN, int COUT, int COP>
__global__ __launch_bounds__(256) void k_transpose_w(
    const float* __restrict__ W, float* __restrict__ Wt)
{
  constexpr int TOT = CIN * 125 * COP;
  int idx = blockIdx.x * 256 + threadIdx.x;
  if (idx >= TOT) return;
  int co = idx % COP;
  int k  = (idx / COP) % 125;
  int ci = idx / (COP * 125);
  Wt[idx] = (co < COUT) ? W[((size_t)co * CIN + ci) * 125 + k] : 0.f;
}

// ---------------- tiled direct 5^3 conv (round-4 verified structure) -------
// in: [B][CIN][DIN(z)][DIN(y)][XSRC(x)] (XSRC<DIN when FUSEX: x-blur fused
// into staging). wt: [CIN][125][COP]. out: [B][COUT][DOUT^3] (+split stride).
// Block: NCB co-groups (COB each) x SPTP spatial threads. Per thread: XB
// consecutive x outputs x COB channels. Weights read via wave-uniform
// (readfirstlane) addresses -> scalar loads. Input tile staged per CIB
// channels in LDS (parity de-interleaved if S==2), window reads b128/b64.
template<int S, int CIN, int CSPLIT, int COUT, int COP, int COB, int NCB,
         int DIN, int XSRC, int DOUT, int PAD, int ZT, int YT, int XB,
         int SPTP, int FUSEX, int XOFF, int CIB>
__global__ __launch_bounds__(256)
void convK(const float* __restrict__ in, const float* __restrict__ wt,
           float* __restrict__ out, size_t split_stride, GaussW gw)
{
  constexpr int K = 5;
  static_assert(DOUT % XB == 0, "XB must divide DOUT");
  constexpr int XQ  = DOUT / XB;
  constexpr int SPT = ZT * YT * XQ;
  static_assert(SPT <= SPTP, "SPTP too small");
  constexpr int NTH = SPTP * NCB;
  static_assert(NTH == 256, "block size 256");
  constexpr int XIN = (DOUT - 1) * S + K;
  constexpr int YIN = (YT - 1) * S + K;
  constexpr int ZIN = (ZT - 1) * S + K;
  constexpr int HXP = (S == 2) ? ((DOUT + 2 + 3) & ~3) : 0;
  constexpr int RW0 = (S == 2) ? (2 * HXP) : ((XIN + 3) & ~3);
  constexpr int RW  = (RW0 % 32 == 0 || RW0 % 32 == 16) ? (RW0 + 4) : RW0;
  constexpr int NROW = ZIN * YIN;
  constexpr int NIN  = NROW * RW;
  static_assert(DOUT % ZT == 0, "ZT must divide DOUT");
  constexpr int NZT = DOUT / ZT;
  constexpr int NYT = (DOUT + YT - 1) / YT;
  constexpr int D2  = DOUT * DOUT;
  constexpr int CI_PER = CIN / CSPLIT;
  static_assert(CI_PER % CIB == 0, "CIB must divide CI_PER");

  __shared__ __align__(16) float s_in[CIB][NIN];

  const int tid = threadIdx.x;
  const int cbg = __builtin_amdgcn_readfirstlane(tid / SPTP);  // wave-uniform
  const int sp  = tid % SPTP;

  const int bxi = blockIdx.x;
  const int yt  = bxi % NYT;
  const int zt  = (bxi / NYT) % NZT;
  const int b   = bxi / (NYT * NZT);
  const int cb  = blockIdx.y;
  const int spl = blockIdx.z;
  const int co0 = cb * (COB * NCB) + cbg * COB;
  const int oz0 = zt * ZT;
  const int oy0 = yt * YT;
  const int ci0 = spl * CI_PER;

  bool act = sp < SPT;
  int txq = act ? sp % XQ : 0;
  int t2  = act ? sp / XQ : 0;
  int tyl = t2 % YT;
  int tzl = t2 / YT;
  act = act && (oy0 + tyl < DOUT);
  if (!act) { txq = 0; tyl = 0; tzl = 0; }

  float acc[XB][COB];
  #pragma unroll
  for (int j = 0; j < XB; ++j)
    #pragma unroll
    for (int c = 0; c < COB; ++c) acc[j][c] = 0.f;

  for (int r = 0; r < CI_PER; r += CIB) {
    __syncthreads();
    // ---- stage CIB input channels (zero-padded; x-blur fused if FUSEX) ----
    for (int i = tid; i < CIB * NIN; i += NTH) {
      int cc = i / NIN;
      int w  = i - cc * NIN;
      int row = w / RW;
      int wx  = w - row * RW;
      int sz = row / YIN;
      int sy = row - sz * YIN;
      int u;
      if (S == 2) u = (wx < HXP) ? (2 * wx) : (wx < 2 * HXP ? 2 * (wx - HXP) + 1 : -1);
      else        u = (wx < XIN) ? wx : -1;
      int gz = oz0 * S + sz - PAD;
      int gy = oy0 * S + sy - PAD;
      int gx = u - PAD;
      float v = 0.f;
      if (u >= 0 && gz >= 0 && gz < DIN && gy >= 0 && gy < DIN &&
          gx >= 0 && gx < DIN) {
        const float* src = in +
            (((size_t)b * CIN + (ci0 + r + cc)) * DIN + gz) * ((size_t)DIN * XSRC) +
            (size_t)gy * XSRC;
        if constexpr (FUSEX) {
          float sacc = 0.f;
          #pragma unroll
          for (int tp = 0; tp < 5; ++tp) {
            int xs = gx + tp - XOFF;
            if (xs >= 0 && xs < XSRC) sacc = fmaf(gw.g[tp], src[xs], sacc);
          }
          v = sacc;
        } else {
          v = src[gx];
        }
      }
      s_in[cc][w] = v;
    }
    __syncthreads();
    // ---- accumulate ----
    #pragma unroll 1
    for (int cc = 0; cc < CIB; ++cc) {
      const int ci = ci0 + r + cc;
      const float* wci = wt + (size_t)ci * 125 * COP + co0;  // wave-uniform
      #pragma unroll 1
      for (int kz = 0; kz < K; ++kz) {
        #pragma unroll 1
        for (int ky = 0; ky < K; ++ky) {
          const float* rp = &s_in[cc][((tzl * S + kz) * YIN + (tyl * S + ky)) * RW];
          float fe[8], fo[8];
          if constexpr (S == 2) {
            const float* ep = rp + XB * txq;
            const float* op = rp + HXP + XB * txq;
            if constexpr ((XB & 3) == 0) {
              float4 a = *(const float4*)ep, b4 = *(const float4*)(ep + 4);
              fe[0]=a.x; fe[1]=a.y; fe[2]=a.z; fe[3]=a.w;
              fe[4]=b4.x; fe[5]=b4.y; fe[6]=b4.z; fe[7]=b4.w;
              float4 c4 = *(const float4*)op, d4 = *(const float4*)(op + 4);
              fo[0]=c4.x; fo[1]=c4.y; fo[2]=c4.z; fo[3]=c4.w;
              fo[4]=d4.x; fo[5]=d4.y; fo[6]=d4.z; fo[7]=d4.w;
            } else if constexpr ((XB & 1) == 0) {
              #pragma unroll
              for (int q = 0; q < 4; ++q) {
                float2 a = *(const float2*)(ep + 2 * q);
                fe[2*q] = a.x; fe[2*q+1] = a.y;
                float2 b2 = *(const float2*)(op + 2 * q);
                fo[2*q] = b2.x; fo[2*q+1] = b2.y;
              }
            } else {
              #pragma unroll
              for (int q = 0; q < XB + 2; ++q) { fe[q] = ep[q]; fo[q] = op[q]; }
              #pragma unroll
              for (int q = XB + 2; q < 8; ++q) { fe[q] = 0.f; fo[q] = 0.f; }
            }
          } else {
            const float* wp0 = rp + XB * txq;
            float4 a = *(const float4*)wp0, b4 = *(const float4*)(wp0 + 4);
            fe[0]=a.x; fe[1]=a.y; fe[2]=a.z; fe[3]=a.w;
            fe[4]=b4.x; fe[5]=b4.y; fe[6]=b4.z; fe[7]=b4.w;
            fo[0]=0.f; fo[1]=0.f; fo[2]=0.f; fo[3]=0.f;
            fo[4]=0.f; fo[5]=0.f; fo[6]=0.f; fo[7]=0.f;
          }
          const float* wk = wci + (kz * 25 + ky * 5) * COP;
          #pragma unroll
          for (int kx = 0; kx < K; ++kx) {
            const float* wp = wk + kx * COP;
            float wv[COB];
            #pragma unroll
            for (int c = 0; c < COB; ++c) wv[c] = wp[c];  // scalar loads
            #pragma unroll
            for (int j = 0; j < XB; ++j) {
              float iv;
              if constexpr (S == 2)
                iv = (kx & 1) ? fo[j + (kx >> 1)] : fe[j + (kx >> 1)];
              else
                iv = fe[j + kx];
              #pragma unroll
              for (int c = 0; c < COB; ++c)
                acc[j][c] = fmaf(iv, wv[c], acc[j][c]);
            }
          }
        }
      }
    }
  }
  // ---- store ----
  if (act) {
    const int oz = oz0 + tzl, oy = oy0 + tyl, ox = txq * XB;
    float* ob = out + (size_t)spl * split_stride;
    #pragma unroll
    for (int c = 0; c < COB; ++c) {
      int co = co0 + c;
      if (co < COUT) {
        float* p = ob + (((size_t)b * COUT + co) * DOUT + oz) * D2 +
                   (size_t)oy * DOUT + ox;
        if constexpr ((XB & 3) == 0) {
          #pragma unroll
          for (int q = 0; q < XB / 4; ++q)
            *(float4*)(p + 4 * q) = make_float4(acc[4*q][c], acc[4*q+1][c],
                                                acc[4*q+2][c], acc[4*q+3][c]);
        } else if constexpr ((XB & 1) == 0) {
          #pragma unroll
          for (int q = 0; q < XB / 2; ++q)
            *(float2*)(p + 2 * q) = make_float2(acc[2*q][c], acc[2*q+1][c]);
        } else {
          #pragma unroll
          for (int j = 0; j < XB; ++j) p[j] = acc[j][c];
        }
      }
    }
  }
}

// ---------------- gated nonlinearity (float4, optional split-K sum) --------
__global__ __launch_bounds__(256) void k_gated4(
    const float* __restrict__ in, const float* __restrict__ in2,
    float* __restrict__ out, int S3v, int Cin, int n_scalar, int n_gate,
    int m1, int d1, int m2, int d2, int m3, int d3, int n_out)
{
  int idx = blockIdx.x * 256 + threadIdx.x;
  int oc = blockIdx.y;
  int b  = blockIdx.z;
  if (idx >= S3v) return;
  size_t S3 = (size_t)S3v * 4;
  auto ld = [&](int ch) {
    size_t o = ((size_t)b * Cin + ch) * S3 + 4 * (size_t)idx;
    float4 v = *(const float4*)(in + o);
    if (in2) {
      float4 w = *(const float4*)(in2 + o);
      v.x += w.x; v.y += w.y; v.z += w.z; v.w += w.w;
    }
    return v;
  };
  float4 val;
  if (oc < n_scalar) {
    float4 v = ld(oc);
    val = make_float4(fmaxf(v.x, 0.f), fmaxf(v.y, 0.f),
                      fmaxf(v.z, 0.f), fmaxf(v.w, 0.f));
  } else {
    int o = oc - n_scalar;
    int gate_ch;
    if (o < m1 * d1) gate_ch = n_scalar + o / d1;
    else if (o - m1 * d1 < m2 * d2) gate_ch = n_scalar + m1 + (o - m1 * d1) / d2;
    else gate_ch = n_scalar + m1 + m2 + (o - m1 * d1 - m2 * d2) / d3;
    float4 v = ld(n_scalar + n_gate + o);
    float4 g = ld(gate_ch);
    val = make_float4(v.x / (1.f + expf(-g.x)), v.y / (1.f + expf(-g.y)),
                      v.z / (1.f + expf(-g.z)), v.w / (1.f + expf(-g.w)));
  }
  *(float4*)(out + ((size_t)b * n_out + oc) * S3 + 4 * (size_t)idx) = val;
}

// ---------------- sum splits + relu + spatial mean -------------------------
__global__ __launch_bounds__(256) void k_relu_avg(
    const float* __restrict__ in, float* __restrict__ h, int nspl,
    size_t sstride)
{
  int bc = blockIdx.x;               // b*64 + c
  const float* p = in + (size_t)bc * 4096;
  float s = 0.f;
  for (int i = threadIdx.x; i < 1024; i += 256) {
    float4 v = *(const float4*)(p + 4 * i);
    for (int k = 1; k < nspl; ++k) {
      float4 w = *(const float4*)(p + (size_t)k * sstride + 4 * i);
      v.x += w.x; v.y += w.y; v.z += w.z; v.w += w.w;
    }
    s += fmaxf(v.x, 0.f) + fmaxf(v.y, 0.f) + fmaxf(v.z, 0.f) + fmaxf(v.w, 0.f);
  }
  #pragma unroll
  for (int off = 32; off > 0; off >>= 1) s += __shfl_down(s, off, 64);
  __shared__ float wsum[4];
  int wid = threadIdx.x >> 6;
  if ((threadIdx.x & 63) == 0) wsum[wid] = s;
  __syncthreads();
  if (threadIdx.x == 0)
    h[bc] = (wsum[0] + wsum[1] + wsum[2] + wsum[3]) * (1.f / 4096.f);
}

// ---------------- final linear [16,64] @ [10,64]^T + b ---------------------
__global__ __launch_bounds__(256) void k_linear(
    const float* __restrict__ h, const float* __restrict__ Wl,
    const float* __restrict__ bl, float* __restrict__ out)
{
  int t = threadIdx.x;
  if (t >= 160) return;
  int b = t / 10, o = t - b * 10;
  const float* hp = h + b * 64;
  const float* wp = Wl + o * 64;
  float s = bl[o];
  #pragma unroll
  for (int c = 0; c < 64; ++c) s = fmaf(hp[c], wp[c], s);
  out[t] = s;
}

extern "C" void kernel_launch(void* const* d_in, const int* in_sizes, int n_in,
                              void* d_out, int out_size, void* d_ws, size_t ws_size,
                              hipStream_t stream)
{
  const float* x  = (const float*)d_in[0];
  const float* W1 = (const float*)d_in[1];
  const float* W2 = (const float*)d_in[2];
  const float* W3 = (const float*)d_in[3];
  const float* W4 = (const float*)d_in[4];
  const float* Wl = (const float*)d_in[5];
  const float* bl = (const float*)d_in[6];
  float* out = (float*)d_out;
  float* ws  = (float*)d_ws;

  // gaussian taps (scale=2): sigma=0.5*sqrt(3), size 5, normalized
  GaussW gw;
  {
    double gv[5], sum = 0.0;
    for (int i = 0; i < 5; ++i) { double r = i - 2; gv[i] = exp(-r * r / 1.5); sum += gv[i]; }
    for (int i = 0; i < 5; ++i) gw.g[i] = (float)(gv[i] / sum);
  }

  // workspace (floats), 64-aligned chunks; two ping-pong regions A,B.
  size_t off = 0;
  auto A = [&](size_t n) { size_t o = off; off += (n + 63) & ~(size_t)63; return o; };
  size_t o_lp  = A(524288);              // z,y-blurred input 16x1x32^3
  size_t o_W1t = A(4000);                // [1][125][32]
  size_t o_W2t = A(300000);              // [25][125][96]
  size_t o_W3t = A(864000);              // [72][125][96]
  size_t o_W4t = A(640000);              // [80][125][64]
  size_t o_h   = A(1024);
  size_t o_A   = A(23040000);            // ping region A
  size_t o_B   = A(22394880);            // ping region B
  if (ws_size < off * sizeof(float)) return;

  float* lp  = ws + o_lp;
  float* W1t = ws + o_W1t;
  float* W2t = ws + o_W2t;
  float* W3t = ws + o_W3t;
  float* W4t = ws + o_W4t;
  float* hb  = ws + o_h;
  float* Ab  = ws + o_A;
  float* Bb  = ws + o_B;

  // weight prep
  k_transpose_w<1, 30, 32><<<16, 256, 0, stream>>>(W1, W1t);
  k_transpose_w<25, 88, 96><<<(300000 + 255) / 256, 256, 0, stream>>>(W2, W2t);
  k_transpose_w<72, 96, 96><<<(864000 + 255) / 256, 256, 0, stream>>>(W3, W3t);
  k_transpose_w<80, 64, 64><<<(640000 + 255) / 256, 256, 0, stream>>>(W4, W4t);

  // input blur (crop): z pass x->A, y pass A->lp; x pass fused into conv1
  blur1d<16, 32, 32, 32, 2, 0><<<(16 * 32 * 32 * 8 + 255) / 256, 256, 0, stream>>>(x, Ab, gw);
  blur1d<16, 32, 32, 32, 1, 0><<<(16 * 32 * 32 * 8 + 255) / 256, 256, 0, stream>>>(Ab, lp, gw);

  // conv1: lp(1, 32^3 virtual, fused x crop-blur) -> B (30, 36^3)
  convK<1, 1, 1, 30, 32, 8, 2, 32, 32, 36, 4, 2, 7, 4, 128, 1, 2, 1>
      <<<dim3(16 * 18 * 6, 2, 1), 256, 0, stream>>>(lp, W1t, Bb, 0, gw);
  // gated1 -> A (25, 36^3)
  k_gated4<<<dim3(46, 25, 16), 256, 0, stream>>>(Bb, nullptr, Ab, 11664, 30, 2, 5,
                                                 2, 3, 2, 5, 1, 7, 25);
  // blur2 (expand): z A->B (40,36,36), y B->A (40,40,36)
  blur1d<400, 36, 36, 36, 2, 1><<<(400 * 40 * 36 * 9 + 255) / 256, 256, 0, stream>>>(Ab, Bb, gw);
  blur1d<400, 40, 36, 36, 1, 1><<<(400 * 40 * 40 * 9 + 255) / 256, 256, 0, stream>>>(Bb, Ab, gw);
  // conv2: A(25, 40^3 virtual, x from 36) -> B (88, 20^3)
  // NCB=4 (3 co-tiles), ZT=2/YT=6 -> LDS 21.8KB, grid 1920
  convK<2, 25, 1, 88, 96, 8, 4, 40, 36, 20, 2, 2, 6, 4, 64, 1, 4, 1>
      <<<dim3(640, 3, 1), 256, 0, stream>>>(Ab, W2t, Bb, 0, gw);
  // gated2 -> A (72, 20^3)
  k_gated4<<<dim3(8, 72, 16), 256, 0, stream>>>(Bb, nullptr, Ab, 2000, 88, 8, 16,
                                                8, 3, 8, 5, 0, 1, 72);
  // blur3 (expand): z A->B (24,20,20), y B->A (24,24,20), x A->B (24,24,24)
  blur1d<1152, 20, 20, 20, 2, 1><<<(1152 * 24 * 20 * 5 + 255) / 256, 256, 0, stream>>>(Ab, Bb, gw);
  blur1d<1152, 24, 20, 20, 1, 1><<<(1152 * 24 * 24 * 5 + 255) / 256, 256, 0, stream>>>(Bb, Ab, gw);
  blur1dx<1152, 24, 24, 20><<<(1152 * 24 * 24 * 6 + 255) / 256, 256, 0, stream>>>(Ab, Bb, gw);
  // conv3: B(72, 24^3) -> A: P0, P1 (each 96, 12^3), split-K=2, LDS 17.4KB
  convK<2, 72, 2, 96, 96, 8, 4, 24, 24, 12, 2, 4, 4, 3, 64, 0, 0, 1>
      <<<dim3(144, 3, 2), 256, 0, stream>>>(Bb, W3t, Ab, 2654208, gw);
  // gated3 (sum splits) -> B (80, 12^3)
  k_gated4<<<dim3(2, 80, 16), 256, 0, stream>>>(Ab, Ab + 2654208, Bb, 432, 96, 16, 16,
                                                8, 3, 8, 5, 0, 1, 80);
  // conv4: B(80, 12^3) -> A: P0..P3 (each 64, 16^3), split-K=4, LDS 5.8KB
  convK<1, 80, 4, 64, 64, 8, 4, 12, 12, 16, 4, 2, 8, 4, 64, 0, 0, 1>
      <<<dim3(256, 2, 4), 256, 0, stream>>>(Bb, W4t, Ab, 4194304, gw);
  // sum splits + relu + spatial mean -> hb[16*64]
  k_relu_avg<<<1024, 256, 0, stream>>>(Ab, hb, 4, 4194304);
  // linear -> out[16*10]
  k_linear<<<1, 256, 0, stream>>>(hb, Wl, bl, out);
}

// Round 8
// 2643.071 us; speedup vs baseline: 2.4351x; 1.3812x over previous
//
#include <hip/hip_runtime.h>
#include <math.h>

// SE3Net forward. convs 2-4 via split-bf16 MFMA (hi/lo decomposition, 3
// products in fp32 accumulators); conv1 (ci=1) stays fp32 vector.
//   blurZ,blurY(x) -> conv1(5^3,p4,+fused x-blur) -> gated
//   -> blurZ,blurY(expand) -> convM2(5^3,s2,p2,+fused x-blur) -> gated
//   -> blurZ,blurY,blurX(expand) -> convM3(5^3,s2,p2) -> gated
//   -> convM4(5^3,p4) -> relu+avg -> linear
// Identity: conv(pad4,s1) is a FULL conv, so downsample(G*(W*x)) ==
// downsample(W*(G_exp*x)) with G_exp on its full support (D->D+4).
// MFMA tiling: D=A·B, M=32 co (wave-per-co-tile), N=32 spatial (2z x 4y x 4x
// patch), K=16 ci chunk. C/D layout per learn_hip m74/m101:
// col=lane&31, row=(reg&3)+8*(reg>>2)+4*(lane>>5).

struct GaussW { float g[5]; };
#define B_ 16

typedef __attribute__((ext_vector_type(8))) short bh8;     // 8 bf16 (4 VGPR)
typedef __attribute__((ext_vector_type(16))) float f32v16; // 32x32 acc
union U128 { uint4 u; bh8 h; };

__device__ inline ushort f2bf(float f) {        // fp32 -> bf16 RNE
  uint u = __float_as_uint(f);
  return (ushort)((u + 0x7FFFu + ((u >> 16) & 1u)) >> 16);
}

// ---------------- separable 1D blur pass along z (AXIS=2) or y (AXIS=1) ----
template<int NBC, int DZ, int DY, int DX, int AXIS, int EXP>
__global__ __launch_bounds__(256) void blur1d(
    const float* __restrict__ in, float* __restrict__ out, GaussW gw)
{
  constexpr int DZO = DZ + ((AXIS == 2 && EXP) ? 4 : 0);
  constexpr int DYO = DY + ((AXIS == 1 && EXP) ? 4 : 0);
  constexpr int OFF = EXP ? 4 : 2;
  constexpr int NV  = DX / 4;
  constexpr int TOT = NBC * DZO * DYO * NV;
  int idx = blockIdx.x * 256 + threadIdx.x;
  if (idx >= TOT) return;
  int xv = idx % NV;
  int t  = idx / NV;
  int y  = t % DYO;
  t /= DYO;
  int z  = t % DZO;
  int bc = t / DZO;
  const float* p = in + (size_t)bc * DZ * DY * DX;
  float4 s = make_float4(0.f, 0.f, 0.f, 0.f);
  #pragma unroll
  for (int k = 0; k < 5; ++k) {
    int c = (AXIS == 2 ? z : y) + k - OFF;
    if (c < 0 || c >= (AXIS == 2 ? DZ : DY)) continue;
    const float4 v = *(const float4*)(p +
        (AXIS == 2 ? ((size_t)c * DY + y) : ((size_t)z * DY + c)) * DX + 4 * xv);
    float g = gw.g[k];
    s.x = fmaf(g, v.x, s.x);
    s.y = fmaf(g, v.y, s.y);
    s.z = fmaf(g, v.z, s.z);
    s.w = fmaf(g, v.w, s.w);
  }
  *(float4*)(out + (((size_t)bc * DZO + z) * DYO + y) * DX + 4 * xv) = s;
}

// ---------------- x-axis expanding blur: (DZ,DY,DXI) -> (DZ,DY,DXI+4) ------
template<int NBC, int DZ, int DY, int DXI>
__global__ __launch_bounds__(256) void blur1dx(
    const float* __restrict__ in, float* __restrict__ out, GaussW gw)
{
  constexpr int DXO = DXI + 4;
  static_assert(DXO % 4 == 0, "DXO must be /4");
  constexpr int NV  = DXO / 4;
  constexpr int TOT = NBC * DZ * DY * NV;
  int idx = blockIdx.x * 256 + threadIdx.x;
  if (idx >= TOT) return;
  int xv = idx % NV;
  int t  = idx / NV;
  int y  = t % DY;
  t /= DY;
  int z  = t % DZ;
  int bc = t / DZ;
  const float* row = in + ((size_t)bc * DZ + z) * DY * DXI + (size_t)y * DXI;
  float win[12];
  #pragma unroll
  for (int q = 0; q < 12; ++q) {
    int gx = 4 * xv + q - 4;
    win[q] = (gx >= 0 && gx < DXI) ? row[gx] : 0.f;
  }
  float o[4];
  #pragma unroll
  for (int q = 0; q < 4; ++q) {
    float s = 0.f;
    #pragma unroll
    for (int k = 0; k < 5; ++k) s = fmaf(gw.g[k], win[q + k], s);
    o[q] = s;
  }
  *(float4*)(out + (((size_t)bc * DZ + z) * DY + y) * DXO + 4 * xv) =
      make_float4(o[0], o[1], o[2], o[3]);
}

// ---------------- weight transpose (conv1): W[co][ci][125] -> Wt[ci][k][COP]
template<int CIN, int COUT, int COP>
__global__ __launch_bounds__(256) void k_transpose_w(
    const float* __restrict__ W, float* __restrict__ Wt)
{
  constexpr int TOT = CIN * 125 * COP;
  int idx = blockIdx.x * 256 + threadIdx.x;
  if (idx >= TOT) return;
  int co = idx % COP;
  int k  = (idx / COP) % 125;
  int ci = idx / (COP * 125);
  Wt[idx] = (co < COUT) ? W[((size_t)co * CIN + ci) * 125 + k] : 0.f;
}

// ---------------- MFMA weight prep: fragment-ordered hi/lo bf16 ------------
// wf[(((chunk*125+tap)*NCOT + cot)*2 + hl)*512 + lane*8 + j]
// lane: co = cot*32 + (lane&31); ci = chunk*16 + (lane>>5)*8 + j.
template<int CIN, int NCHUNK, int COUT, int NCOT>
__global__ __launch_bounds__(256) void k_prep_w(
    const float* __restrict__ W, ushort* __restrict__ wf)
{
  constexpr int TOT = NCHUNK * 125 * NCOT * 2 * 512;
  int idx = blockIdx.x * 256 + threadIdx.x;
  if (idx >= TOT) return;
  int j    = idx & 7;
  int lane = (idx >> 3) & 63;
  int hl   = (idx >> 9) & 1;
  int t2   = idx >> 10;          // (chunk*125+tap)*NCOT + cot
  int cot  = t2 % NCOT;
  int kst  = t2 / NCOT;
  int tap  = kst % 125;
  int chunk = kst / 125;
  int ci = chunk * 16 + (lane >> 5) * 8 + j;
  int co = cot * 32 + (lane & 31);
  float w = 0.f;
  if (ci < CIN && co < COUT) w = W[((size_t)co * CIN + ci) * 125 + tap];
  ushort hi = f2bf(w);
  ushort v = hi;
  if (hl) { float hif = __uint_as_float((uint)hi << 16); v = f2bf(w - hif); }
  wf[idx] = v;
}

// ---------------- MFMA conv: 5^3, stride S, pad PAD ------------------------
// in: [B][CIN][DIN][DIN][XSRC] fp32 (FUSEX: x-blur fused in staging).
// Block: NCOT waves (wave = one 32-co tile), spatial patch 2z x 4y x 4x.
// Per ci-chunk(16): stage hi/lo bf16 channel-last in LDS; per tap: A-frag
// from prepped global (uint4), B-frag from LDS (uint2 x4), 3 MFMAs.
template<int S, int CIN, int NCHUNK, int COUT, int NCOT, int DIN, int XSRC,
         int DOUT, int PAD, int FUSEX, int XOFF>
__global__ __launch_bounds__(NCOT * 64)
void convM(const float* __restrict__ in, const ushort* __restrict__ wf,
           float* __restrict__ out, GaussW gw)
{
  constexpr int ZT = 2, YT = 4, XT = 4;
  constexpr int ZIN = (ZT - 1) * S + 5;
  constexpr int YIN = (YT - 1) * S + 5;
  constexpr int XIN = (XT - 1) * S + 5;
  constexpr int NPTS = ZIN * YIN * XIN;
  constexpr int RUS = 36;              // ushorts/pt row: 16 hi,16 lo,4 pad
  constexpr int NTH = NCOT * 64;
  constexpr int NXT = DOUT / XT, NYT = DOUT / YT, NZT = DOUT / ZT;
  static_assert(DOUT % XT == 0 && DOUT % YT == 0 && DOUT % ZT == 0, "tiles");
  constexpr int D2 = DOUT * DOUT;

  __shared__ __align__(16) uint s_in[NPTS * (RUS / 2)];
  ushort* s_us = (ushort*)s_in;

  const int tid  = threadIdx.x;
  const int lane = tid & 63;
  const int cot  = tid >> 6;
  int bxi = blockIdx.x;
  const int xt = bxi % NXT; bxi /= NXT;
  const int yt = bxi % NYT; bxi /= NYT;
  const int zt = bxi % NZT;
  const int b  = bxi / NZT;
  const int z0 = zt * ZT, y0 = yt * YT, x0 = xt * XT;

  const int n  = lane & 31, g = lane >> 5;
  const int zp = n >> 4, ny = (n >> 2) & 3, nx = n & 3;
  const int zl0 = S * zp, yl0 = S * ny, xl0 = S * nx;

  f32v16 ahh, ahl, alh;
  #pragma unroll
  for (int i = 0; i < 16; ++i) { ahh[i] = 0.f; ahl[i] = 0.f; alh[i] = 0.f; }

  #pragma unroll 1
  for (int chunk = 0; chunk < NCHUNK; ++chunk) {
    __syncthreads();
    // ---- stage 16 ci (hi/lo bf16, zero-padded, optional fused x-blur) ----
    #pragma unroll 1
    for (int e = tid; e < 16 * NPTS; e += NTH) {
      int cil = e / NPTS;
      int pt  = e - cil * NPTS;
      int sz = pt / (YIN * XIN);
      int r2 = pt - sz * (YIN * XIN);
      int sy = r2 / XIN;
      int sx = r2 - sy * XIN;
      int ci = chunk * 16 + cil;
      int gz = z0 * S + sz - PAD;
      int gy = y0 * S + sy - PAD;
      int gx = x0 * S + sx - PAD;
      float v = 0.f;
      if (ci < CIN && gz >= 0 && gz < DIN && gy >= 0 && gy < DIN) {
        const float* src = in +
            (((size_t)b * CIN + ci) * DIN + gz) * ((size_t)DIN * XSRC) +
            (size_t)gy * XSRC;
        if constexpr (FUSEX) {
          #pragma unroll
          for (int t = 0; t < 5; ++t) {
            int xs = gx - XOFF + t;
            if (xs >= 0 && xs < XSRC) v = fmaf(gw.g[t], src[xs], v);
          }
        } else {
          if (gx >= 0 && gx < XSRC) v = src[gx];
        }
      }
      ushort hi = f2bf(v);
      float hif = __uint_as_float((uint)hi << 16);
      ushort lo = f2bf(v - hif);
      s_us[pt * RUS + cil]      = hi;
      s_us[pt * RUS + 16 + cil] = lo;
    }
    __syncthreads();
    // ---- compute 125 taps ----
    const ushort* wfc = wf + (size_t)chunk * 125 * NCOT * 2 * 512;
    #pragma unroll 1
    for (int kz = 0; kz < 5; ++kz) {
      #pragma unroll 1
      for (int ky = 0; ky < 5; ++ky) {
        const int rowb = ((zl0 + kz) * YIN + (yl0 + ky)) * XIN + xl0;
        for (int kx = 0; kx < 5; ++kx) {
          int tap = (kz * 5 + ky) * 5 + kx;
          const uint4* ap =
              (const uint4*)(wfc + (size_t)((tap * NCOT + cot) * 2) * 512);
          U128 wa, wl;
          wa.u = ap[lane];        // A hi fragment
          wl.u = ap[64 + lane];   // A lo fragment
          int pt = rowb + kx;
          const uint2* hp = (const uint2*)(s_us + pt * RUS + 8 * g);
          uint2 h0 = hp[0], h1 = hp[1];
          const uint2* lp = (const uint2*)(s_us + pt * RUS + 16 + 8 * g);
          uint2 l0 = lp[0], l1 = lp[1];
          U128 bh, bl;
          bh.u = make_uint4(h0.x, h0.y, h1.x, h1.y);
          bl.u = make_uint4(l0.x, l0.y, l1.x, l1.y);
          ahh = __builtin_amdgcn_mfma_f32_32x32x16_bf16(wa.h, bh.h, ahh, 0, 0, 0);
          ahl = __builtin_amdgcn_mfma_f32_32x32x16_bf16(wa.h, bl.h, ahl, 0, 0, 0);
          alh = __builtin_amdgcn_mfma_f32_32x32x16_bf16(wl.h, bh.h, alh, 0, 0, 0);
        }
      }
    }
  }
  // ---- store: col=lane&31 -> n, row=(r&3)+8*(r>>2)+4*g -> co-within-tile --
  #pragma unroll
  for (int r = 0; r < 16; ++r) {
    int co = cot * 32 + (r & 3) + 8 * (r >> 2) + 4 * g;
    if (co < COUT) {
      float s = ahh[r] + ahl[r] + alh[r];
      out[(((size_t)b * COUT + co) * DOUT + (z0 + zp)) * D2 +
          (size_t)(y0 + ny) * DOUT + (x0 + nx)] = s;
    }
  }
}

// ---------------- fp32 tiled conv (conv1 only, round-4 verified) -----------
template<int S, int CIN, int CSPLIT, int COUT, int COP, int COB, int NCB,
         int DIN, int XSRC, int DOUT, int PAD, int ZT, int YT, int XB,
         int SPTP, int FUSEX, int XOFF, int CIB>
__global__ __launch_bounds__(256)
void convK(const float* __restrict__ in, const float* __restrict__ wt,
           float* __restrict__ out, size_t split_stride, GaussW gw)
{
  constexpr int K = 5;
  static_assert(DOUT % XB == 0, "XB must divide DOUT");
  constexpr int XQ  = DOUT / XB;
  constexpr int SPT = ZT * YT * XQ;
  static_assert(SPT <= SPTP, "SPTP too small");
  constexpr int NTH = SPTP * NCB;
  static_assert(NTH == 256, "block size 256");
  constexpr int XIN = (DOUT - 1) * S + K;
  constexpr int YIN = (YT - 1) * S + K;
  constexpr int ZIN = (ZT - 1) * S + K;
  constexpr int HXP = (S == 2) ? ((DOUT + 2 + 3) & ~3) : 0;
  constexpr int RW0 = (S == 2) ? (2 * HXP) : ((XIN + 3) & ~3);
  constexpr int RW  = (RW0 % 32 == 0 || RW0 % 32 == 16) ? (RW0 + 4) : RW0;
  constexpr int NROW = ZIN * YIN;
  constexpr int NIN  = NROW * RW;
  static_assert(DOUT % ZT == 0, "ZT must divide DOUT");
  constexpr int NZT = DOUT / ZT;
  constexpr int NYT = (DOUT + YT - 1) / YT;
  constexpr int D2  = DOUT * DOUT;
  constexpr int CI_PER = CIN / CSPLIT;
  static_assert(CI_PER % CIB == 0, "CIB must divide CI_PER");

  __shared__ __align__(16) float s_in[CIB][NIN];

  const int tid = threadIdx.x;
  const int cbg = __builtin_amdgcn_readfirstlane(tid / SPTP);
  const int sp  = tid % SPTP;

  const int bxi = blockIdx.x;
  const int yt  = bxi % NYT;
  const int zt  = (bxi / NYT) % NZT;
  const int b   = bxi / (NYT * NZT);
  const int cb  = blockIdx.y;
  const int spl = blockIdx.z;
  const int co0 = cb * (COB * NCB) + cbg * COB;
  const int oz0 = zt * ZT;
  const int oy0 = yt * YT;
  const int ci0 = spl * CI_PER;

  bool act = sp < SPT;
  int txq = act ? sp % XQ : 0;
  int t2  = act ? sp / XQ : 0;
  int tyl = t2 % YT;
  int tzl = t2 / YT;
  act = act && (oy0 + tyl < DOUT);
  if (!act) { txq = 0; tyl = 0; tzl = 0; }

  float acc[XB][COB];
  #pragma unroll
  for (int j = 0; j < XB; ++j)
    #pragma unroll
    for (int c = 0; c < COB; ++c) acc[j][c] = 0.f;

  for (int r = 0; r < CI_PER; r += CIB) {
    __syncthreads();
    for (int i = tid; i < CIB * NIN; i += NTH) {
      int cc = i / NIN;
      int w  = i - cc * NIN;
      int row = w / RW;
      int wx  = w - row * RW;
      int sz = row / YIN;
      int sy = row - sz * YIN;
      int u;
      if (S == 2) u = (wx < HXP) ? (2 * wx) : (wx < 2 * HXP ? 2 * (wx - HXP) + 1 : -1);
      else        u = (wx < XIN) ? wx : -1;
      int gz = oz0 * S + sz - PAD;
      int gy = oy0 * S + sy - PAD;
      int gx = u - PAD;
      float v = 0.f;
      if (u >= 0 && gz >= 0 && gz < DIN && gy >= 0 && gy < DIN &&
          gx >= 0 && gx < DIN) {
        const float* src = in +
            (((size_t)b * CIN + (ci0 + r + cc)) * DIN + gz) * ((size_t)DIN * XSRC) +
            (size_t)gy * XSRC;
        if constexpr (FUSEX) {
          float sacc = 0.f;
          #pragma unroll
          for (int tp = 0; tp < 5; ++tp) {
            int xs = gx + tp - XOFF;
            if (xs >= 0 && xs < XSRC) sacc = fmaf(gw.g[tp], src[xs], sacc);
          }
          v = sacc;
        } else {
          v = src[gx];
        }
      }
      s_in[cc][w] = v;
    }
    __syncthreads();
    #pragma unroll 1
    for (int cc = 0; cc < CIB; ++cc) {
      const int ci = ci0 + r + cc;
      const float* wci = wt + (size_t)ci * 125 * COP + co0;
      #pragma unroll 1
      for (int kz = 0; kz < K; ++kz) {
        #pragma unroll 1
        for (int ky = 0; ky < K; ++ky) {
          const float* rp = &s_in[cc][((tzl * S + kz) * YIN + (tyl * S + ky)) * RW];
          float fe[8], fo[8];
          if constexpr (S == 2) {
            const float* ep = rp + XB * txq;
            const float* op = rp + HXP + XB * txq;
            #pragma unroll
            for (int q = 0; q < 4; ++q) {
              float2 a = *(const float2*)(ep + 2 * q);
              fe[2*q] = a.x; fe[2*q+1] = a.y;
              float2 b2 = *(const float2*)(op + 2 * q);
              fo[2*q] = b2.x; fo[2*q+1] = b2.y;
            }
          } else {
            const float* wp0 = rp + XB * txq;
            float4 a = *(const float4*)wp0, b4 = *(const float4*)(wp0 + 4);
            fe[0]=a.x; fe[1]=a.y; fe[2]=a.z; fe[3]=a.w;
            fe[4]=b4.x; fe[5]=b4.y; fe[6]=b4.z; fe[7]=b4.w;
            fo[0]=0.f; fo[1]=0.f; fo[2]=0.f; fo[3]=0.f;
            fo[4]=0.f; fo[5]=0.f; fo[6]=0.f; fo[7]=0.f;
          }
          const float* wk = wci + (kz * 25 + ky * 5) * COP;
          #pragma unroll
          for (int kx = 0; kx < K; ++kx) {
            const float* wp = wk + kx * COP;
            float wv[COB];
            #pragma unroll
            for (int c = 0; c < COB; ++c) wv[c] = wp[c];
            #pragma unroll
            for (int j = 0; j < XB; ++j) {
              float iv;
              if constexpr (S == 2)
                iv = (kx & 1) ? fo[j + (kx >> 1)] : fe[j + (kx >> 1)];
              else
                iv = fe[j + kx];
              #pragma unroll
              for (int c = 0; c < COB; ++c)
                acc[j][c] = fmaf(iv, wv[c], acc[j][c]);
            }
          }
        }
      }
    }
  }
  if (act) {
    const int oz = oz0 + tzl, oy = oy0 + tyl, ox = txq * XB;
    float* ob = out + (size_t)spl * split_stride;
    #pragma unroll
    for (int c = 0; c < COB; ++c) {
      int co = co0 + c;
      if (co < COUT) {
        float* p = ob + (((size_t)b * COUT + co) * DOUT + oz) * D2 +
                   (size_t)oy * DOUT + ox;
        #pragma unroll
        for (int q = 0; q < XB / 2; ++q)
          *(float2*)(p + 2 * q) = make_float2(acc[2*q][c], acc[2*q+1][c]);
      }
    }
  }
}

// ---------------- gated nonlinearity (float4, optional split-K sum) --------
__global__ __launch_bounds__(256) void k_gated4(
    const float* __restrict__ in, const float* __restrict__ in2,
    float* __restrict__ out, int S3v, int Cin, int n_scalar, int n_gate,
    int m1, int d1, int m2, int d2, int m3, int d3, int n_out)
{
  int idx = blockIdx.x * 256 + threadIdx.x;
  int oc = blockIdx.y;
  int b  = blockIdx.z;
  if (idx >= S3v) return;
  size_t S3 = (size_t)S3v * 4;
  auto ld = [&](int ch) {
    size_t o = ((size_t)b * Cin + ch) * S3 + 4 * (size_t)idx;
    float4 v = *(const float4*)(in + o);
    if (in2) {
      float4 w = *(const float4*)(in2 + o);
      v.x += w.x; v.y += w.y; v.z += w.z; v.w += w.w;
    }
    return v;
  };
  float4 val;
  if (oc < n_scalar) {
    float4 v = ld(oc);
    val = make_float4(fmaxf(v.x, 0.f), fmaxf(v.y, 0.f),
                      fmaxf(v.z, 0.f), fmaxf(v.w, 0.f));
  } else {
    int o = oc - n_scalar;
    int gate_ch;
    if (o < m1 * d1) gate_ch = n_scalar + o / d1;
    else if (o - m1 * d1 < m2 * d2) gate_ch = n_scalar + m1 + (o - m1 * d1) / d2;
    else gate_ch = n_scalar + m1 + m2 + (o - m1 * d1 - m2 * d2) / d3;
    float4 v = ld(n_scalar + n_gate + o);
    float4 g = ld(gate_ch);
    val = make_float4(v.x / (1.f + expf(-g.x)), v.y / (1.f + expf(-g.y)),
                      v.z / (1.f + expf(-g.z)), v.w / (1.f + expf(-g.w)));
  }
  *(float4*)(out + ((size_t)b * n_out + oc) * S3 + 4 * (size_t)idx) = val;
}

// ---------------- relu + spatial mean --------------------------------------
__global__ __launch_bounds__(256) void k_relu_avg(
    const float* __restrict__ in, float* __restrict__ h)
{
  int bc = blockIdx.x;               // b*64 + c
  const float* p = in + (size_t)bc * 4096;
  float s = 0.f;
  for (int i = threadIdx.x; i < 1024; i += 256) {
    float4 v = *(const float4*)(p + 4 * i);
    s += fmaxf(v.x, 0.f) + fmaxf(v.y, 0.f) + fmaxf(v.z, 0.f) + fmaxf(v.w, 0.f);
  }
  #pragma unroll
  for (int off = 32; off > 0; off >>= 1) s += __shfl_down(s, off, 64);
  __shared__ float wsum[4];
  int wid = threadIdx.x >> 6;
  if ((threadIdx.x & 63) == 0) wsum[wid] = s;
  __syncthreads();
  if (threadIdx.x == 0)
    h[bc] = (wsum[0] + wsum[1] + wsum[2] + wsum[3]) * (1.f / 4096.f);
}

// ---------------- final linear [16,64] @ [10,64]^T + b ---------------------
__global__ __launch_bounds__(256) void k_linear(
    const float* __restrict__ h, const float* __restrict__ Wl,
    const float* __restrict__ bl, float* __restrict__ out)
{
  int t = threadIdx.x;
  if (t >= 160) return;
  int b = t / 10, o = t - b * 10;
  const float* hp = h + b * 64;
  const float* wp = Wl + o * 64;
  float s = bl[o];
  #pragma unroll
  for (int c = 0; c < 64; ++c) s = fmaf(hp[c], wp[c], s);
  out[t] = s;
}

extern "C" void kernel_launch(void* const* d_in, const int* in_sizes, int n_in,
                              void* d_out, int out_size, void* d_ws, size_t ws_size,
                              hipStream_t stream)
{
  const float* x  = (const float*)d_in[0];
  const float* W1 = (const float*)d_in[1];
  const float* W2 = (const float*)d_in[2];
  const float* W3 = (const float*)d_in[3];
  const float* W4 = (const float*)d_in[4];
  const float* Wl = (const float*)d_in[5];
  const float* bl = (const float*)d_in[6];
  float* out = (float*)d_out;
  float* ws  = (float*)d_ws;

  // gaussian taps (scale=2): sigma=0.5*sqrt(3), size 5, normalized
  GaussW gw;
  {
    double gv[5], sum = 0.0;
    for (int i = 0; i < 5; ++i) { double r = i - 2; gv[i] = exp(-r * r / 1.5); sum += gv[i]; }
    for (int i = 0; i < 5; ++i) gw.g[i] = (float)(gv[i] / sum);
  }

  // workspace (floats), 64-aligned chunks; two ping-pong regions A,B.
  size_t off = 0;
  auto A = [&](size_t n) { size_t o = off; off += (n + 63) & ~(size_t)63; return o; };
  size_t o_lp  = A(524288);              // z,y-blurred input 16x1x32^3
  size_t o_W1t = A(4000);                // conv1 [1][125][32]
  size_t o_Wf2 = A(384000);              // conv2 MFMA frags (768k ushort)
  size_t o_Wf3 = A(960000);              // conv3 MFMA frags (1.92M ushort)
  size_t o_Wf4 = A(640000);              // conv4 MFMA frags (1.28M ushort)
  size_t o_h   = A(1024);
  size_t o_A   = A(23040000);            // ping region A
  size_t o_B   = A(22394880);            // ping region B
  if (ws_size < off * sizeof(float)) return;

  float*  lp  = ws + o_lp;
  float*  W1t = ws + o_W1t;
  ushort* Wf2 = (ushort*)(ws + o_Wf2);
  ushort* Wf3 = (ushort*)(ws + o_Wf3);
  ushort* Wf4 = (ushort*)(ws + o_Wf4);
  float*  hb  = ws + o_h;
  float*  Ab  = ws + o_A;
  float*  Bb  = ws + o_B;

  // weight prep
  k_transpose_w<1, 30, 32><<<16, 256, 0, stream>>>(W1, W1t);
  k_prep_w<25, 2, 88, 3><<<(768000 + 255) / 256, 256, 0, stream>>>(W2, Wf2);
  k_prep_w<72, 5, 96, 3><<<(1920000 + 255) / 256, 256, 0, stream>>>(W3, Wf3);
  k_prep_w<80, 5, 64, 2><<<(1280000 + 255) / 256, 256, 0, stream>>>(W4, Wf4);

  // input blur (crop): z pass x->A, y pass A->lp; x pass fused into conv1
  blur1d<16, 32, 32, 32, 2, 0><<<(16 * 32 * 32 * 8 + 255) / 256, 256, 0, stream>>>(x, Ab, gw);
  blur1d<16, 32, 32, 32, 1, 0><<<(16 * 32 * 32 * 8 + 255) / 256, 256, 0, stream>>>(Ab, lp, gw);

  // conv1 (fp32): lp(1, 32^3 virtual, fused x crop-blur) -> B (30, 36^3)
  convK<1, 1, 1, 30, 32, 8, 2, 32, 32, 36, 4, 2, 7, 4, 128, 1, 2, 1>
      <<<dim3(16 * 18 * 6, 2, 1), 256, 0, stream>>>(lp, W1t, Bb, 0, gw);
  // gated1 -> A (25, 36^3)
  k_gated4<<<dim3(46, 25, 16), 256, 0, stream>>>(Bb, nullptr, Ab, 11664, 30, 2, 5,
                                                 2, 3, 2, 5, 1, 7, 25);
  // blur2 (expand): z A->B (40,36,36), y B->A (40,40,36)
  blur1d<400, 36, 36, 36, 2, 1><<<(400 * 40 * 36 * 9 + 255) / 256, 256, 0, stream>>>(Ab, Bb, gw);
  blur1d<400, 40, 36, 36, 1, 1><<<(400 * 40 * 40 * 9 + 255) / 256, 256, 0, stream>>>(Bb, Ab, gw);
  // conv2 (MFMA): A(25, 40^3 virtual, x from 36) -> B (88, 20^3)
  convM<2, 25, 2, 88, 3, 40, 36, 20, 2, 1, 4>
      <<<dim3(16 * 10 * 5 * 5), 192, 0, stream>>>(Ab, Wf2, Bb, gw);
  // gated2 -> A (72, 20^3)
  k_gated4<<<dim3(8, 72, 16), 256, 0, stream>>>(Bb, nullptr, Ab, 2000, 88, 8, 16,
                                                8, 3, 8, 5, 0, 1, 72);
  // blur3 (expand): z A->B (24,20,20), y B->A (24,24,20), x A->B (24,24,24)
  blur1d<1152, 20, 20, 20, 2, 1><<<(1152 * 24 * 20 * 5 + 255) / 256, 256, 0, stream>>>(Ab, Bb, gw);
  blur1d<1152, 24, 20, 20, 1, 1><<<(1152 * 24 * 24 * 5 + 255) / 256, 256, 0, stream>>>(Bb, Ab, gw);
  blur1dx<1152, 24, 24, 20><<<(1152 * 24 * 24 * 6 + 255) / 256, 256, 0, stream>>>(Ab, Bb, gw);
  // conv3 (MFMA): B(72, 24^3) -> A (96, 12^3)  [no split-K needed]
  convM<2, 72, 5, 96, 3, 24, 24, 12, 2, 0, 0>
      <<<dim3(16 * 6 * 3 * 3), 192, 0, stream>>>(Bb, Wf3, Ab, gw);
  // gated3 -> B (80, 12^3)
  k_gated4<<<dim3(2, 80, 16), 256, 0, stream>>>(Ab, nullptr, Bb, 432, 96, 16, 16,
                                                8, 3, 8, 5, 0, 1, 80);
  // conv4 (MFMA): B(80, 12^3) -> A (64, 16^3)
  convM<1, 80, 5, 64, 2, 12, 12, 16, 4, 0, 0>
      <<<dim3(16 * 8 * 4 * 4), 128, 0, stream>>>(Bb, Wf4, Ab, gw);
  // relu + spatial mean -> hb[16*64]
  k_relu_avg<<<1024, 256, 0, stream>>>(Ab, hb);
  // linear -> out[16*10]
  k_linear<<<1, 256, 0, stream>>>(hb, Wl, bl, out);
}

// Round 9
// 2336.757 us; speedup vs baseline: 2.7543x; 1.1311x over previous
//
#include <hip/hip_runtime.h>
#include <math.h>

// SE3Net forward. convs 2-4 via split-bf16 MFMA (hi/lo, 3 products, fp32 acc);
// conv1 (ci=1) fp32 vector. Activations for MFMA convs are PRE-PACKED in
// global as uint{bf16hi,bf16lo} by the last blur pass (blur1dx_cvt) or by a
// packed-output gated (gated3), so convM staging is 1 uint load + 2 shifts.
//   blurZ,blurY(x) -> conv1(5^3,p4,+fused x-blur) -> gated
//   -> blurZ,blurY,blurXcvt(expand) -> convM2(5^3,s2,p2) -> gated
//   -> blurZ,blurY,blurXcvt(expand) -> convM3(5^3,s2,p2) -> gatedPack
//   -> convM4(5^3,p4) -> relu+avg -> linear
// MFMA tiling: M=32 co (wave-per-co-tile), N=32 spatial (2z x 4y x 4x),
// K=16 ci. C/D layout (learn_hip m74/m101): col=lane&31,
// row=(reg&3)+8*(reg>>2)+4*(lane>>5).

struct GaussW { float g[5]; };
#define B_ 16

typedef __attribute__((ext_vector_type(8))) short bh8;     // 8 bf16 (4 VGPR)
typedef __attribute__((ext_vector_type(16))) float f32v16; // 32x32 acc
union U128 { uint4 u; bh8 h; };

__device__ inline ushort f2bf(float f) {        // fp32 -> bf16 RNE
  uint u = __float_as_uint(f);
  return (ushort)((u + 0x7FFFu + ((u >> 16) & 1u)) >> 16);
}
__device__ inline uint packbf(float v) {        // (hi<<16)|lo
  ushort hi = f2bf(v);
  float hif = __uint_as_float((uint)hi << 16);
  ushort lo = f2bf(v - hif);
  return ((uint)hi << 16) | lo;
}

// ---------------- separable 1D blur pass along z (AXIS=2) or y (AXIS=1) ----
template<int NBC, int DZ, int DY, int DX, int AXIS, int EXP>
__global__ __launch_bounds__(256) void blur1d(
    const float* __restrict__ in, float* __restrict__ out, GaussW gw)
{
  constexpr int DZO = DZ + ((AXIS == 2 && EXP) ? 4 : 0);
  constexpr int DYO = DY + ((AXIS == 1 && EXP) ? 4 : 0);
  constexpr int OFF = EXP ? 4 : 2;
  constexpr int NV  = DX / 4;
  constexpr int TOT = NBC * DZO * DYO * NV;
  int idx = blockIdx.x * 256 + threadIdx.x;
  if (idx >= TOT) return;
  int xv = idx % NV;
  int t  = idx / NV;
  int y  = t % DYO;
  t /= DYO;
  int z  = t % DZO;
  int bc = t / DZO;
  const float* p = in + (size_t)bc * DZ * DY * DX;
  float4 s = make_float4(0.f, 0.f, 0.f, 0.f);
  #pragma unroll
  for (int k = 0; k < 5; ++k) {
    int c = (AXIS == 2 ? z : y) + k - OFF;
    if (c < 0 || c >= (AXIS == 2 ? DZ : DY)) continue;
    const float4 v = *(const float4*)(p +
        (AXIS == 2 ? ((size_t)c * DY + y) : ((size_t)z * DY + c)) * DX + 4 * xv);
    float g = gw.g[k];
    s.x = fmaf(g, v.x, s.x);
    s.y = fmaf(g, v.y, s.y);
    s.z = fmaf(g, v.z, s.z);
    s.w = fmaf(g, v.w, s.w);
  }
  *(float4*)(out + (((size_t)bc * DZO + z) * DYO + y) * DX + 4 * xv) = s;
}

// ---- x-axis expanding blur + bf16 hi/lo pack: (DZ,DY,DXI) -> (DZ,DY,DXI+4)
template<int NBC, int DZ, int DY, int DXI>
__global__ __launch_bounds__(256) void blur1dx_cvt(
    const float* __restrict__ in, uint* __restrict__ out, GaussW gw)
{
  constexpr int DXO = DXI + 4;
  static_assert(DXO % 4 == 0, "DXO must be /4");
  constexpr int NV  = DXO / 4;
  constexpr int TOT = NBC * DZ * DY * NV;
  int idx = blockIdx.x * 256 + threadIdx.x;
  if (idx >= TOT) return;
  int xv = idx % NV;
  int t  = idx / NV;
  int y  = t % DY;
  t /= DY;
  int z  = t % DZ;
  int bc = t / DZ;
  const float* row = in + ((size_t)bc * DZ + z) * DY * DXI + (size_t)y * DXI;
  float win[12];
  #pragma unroll
  for (int q = 0; q < 12; ++q) {
    int gx = 4 * xv + q - 4;
    win[q] = (gx >= 0 && gx < DXI) ? row[gx] : 0.f;
  }
  uint4 po;
  uint* pp = (uint*)&po;
  #pragma unroll
  for (int q = 0; q < 4; ++q) {
    float s = 0.f;
    #pragma unroll
    for (int k = 0; k < 5; ++k) s = fmaf(gw.g[k], win[q + k], s);
    pp[q] = packbf(s);
  }
  *(uint4*)(out + (((size_t)bc * DZ + z) * DY + y) * DXO + 4 * xv) = po;
}

// ---------------- weight transpose (conv1): W[co][ci][125] -> Wt[ci][k][COP]
template<int CIN, int COUT, int COP>
__global__ __launch_bounds__(256) void k_transpose_w(
    const float* __restrict__ W, float* __restrict__ Wt)
{
  constexpr int TOT = CIN * 125 * COP;
  int idx = blockIdx.x * 256 + threadIdx.x;
  if (idx >= TOT) return;
  int co = idx % COP;
  int k  = (idx / COP) % 125;
  int ci = idx / (COP * 125);
  Wt[idx] = (co < COUT) ? W[((size_t)co * CIN + ci) * 125 + k] : 0.f;
}

// ---------------- MFMA weight prep: fragment-ordered hi/lo bf16 ------------
// wf[(((chunk*125+tap)*NCOT + cot)*2 + hl)*512 + lane*8 + j]
// lane: co = cot*32 + (lane&31); ci = chunk*16 + (lane>>5)*8 + j.
template<int CIN, int NCHUNK, int COUT, int NCOT>
__global__ __launch_bounds__(256) void k_prep_w(
    const float* __restrict__ W, ushort* __restrict__ wf)
{
  constexpr int TOT = NCHUNK * 125 * NCOT * 2 * 512;
  int idx = blockIdx.x * 256 + threadIdx.x;
  if (idx >= TOT) return;
  int j    = idx & 7;
  int lane = (idx >> 3) & 63;
  int hl   = (idx >> 9) & 1;
  int t2   = idx >> 10;          // (chunk*125+tap)*NCOT + cot
  int cot  = t2 % NCOT;
  int kst  = t2 / NCOT;
  int tap  = kst % 125;
  int chunk = kst / 125;
  int ci = chunk * 16 + (lane >> 5) * 8 + j;
  int co = cot * 32 + (lane & 31);
  float w = 0.f;
  if (ci < CIN && co < COUT) w = W[((size_t)co * CIN + ci) * 125 + tap];
  ushort hi = f2bf(w);
  ushort v = hi;
  if (hl) { float hif = __uint_as_float((uint)hi << 16); v = f2bf(w - hif); }
  wf[idx] = v;
}

// ---------------- MFMA conv: 5^3, stride S, pad PAD, packed-uint input -----
// in: [B][CIN][DIN][DIN][DIN] uint (bf16 hi<<16 | lo).
// Block: NCOT waves (wave = one 32-co tile), spatial patch 2z x 4y x 4x.
// Per ci-chunk(16): stage hi/lo bf16 in LDS (1 uint load + 2 shifts/elem);
// per tap: A-frag from prepped global (uint4), B-frag from LDS, 3 MFMAs.
template<int S, int CIN, int NCHUNK, int COUT, int NCOT, int DIN, int DOUT,
         int PAD>
__global__ __launch_bounds__(NCOT * 64)
void convM(const uint* __restrict__ in, const ushort* __restrict__ wf,
           float* __restrict__ out)
{
  constexpr int ZT = 2, YT = 4, XT = 4;
  constexpr int ZIN = (ZT - 1) * S + 5;
  constexpr int YIN = (YT - 1) * S + 5;
  constexpr int XIN = (XT - 1) * S + 5;
  constexpr int NPTS = ZIN * YIN * XIN;
  constexpr int RUS = 36;              // ushorts/pt: 16 hi,16 lo,4 pad
  constexpr int NTH = NCOT * 64;
  constexpr int NXT = DOUT / XT, NYT = DOUT / YT, NZT = DOUT / ZT;
  static_assert(DOUT % XT == 0 && DOUT % YT == 0 && DOUT % ZT == 0, "tiles");
  constexpr int D2 = DOUT * DOUT;

  __shared__ __align__(16) uint s_in[NPTS * (RUS / 2)];
  ushort* s_us = (ushort*)s_in;

  const int tid  = threadIdx.x;
  const int lane = tid & 63;
  const int cot  = tid >> 6;
  int bxi = blockIdx.x;
  const int xt = bxi % NXT; bxi /= NXT;
  const int yt = bxi % NYT; bxi /= NYT;
  const int zt = bxi % NZT;
  const int b  = bxi / NZT;
  const int z0 = zt * ZT, y0 = yt * YT, x0 = xt * XT;

  const int n  = lane & 31, g = lane >> 5;
  const int zp = n >> 4, ny = (n >> 2) & 3, nx = n & 3;
  const int zl0 = S * zp, yl0 = S * ny, xl0 = S * nx;

  f32v16 ahh, ahl, alh;
  #pragma unroll
  for (int i = 0; i < 16; ++i) { ahh[i] = 0.f; ahl[i] = 0.f; alh[i] = 0.f; }

  #pragma unroll 1
  for (int chunk = 0; chunk < NCHUNK; ++chunk) {
    __syncthreads();
    // ---- stage 16 ci (packed uint -> hi/lo ushorts, zero-padded) ----
    #pragma unroll 1
    for (int e = tid; e < 16 * NPTS; e += NTH) {
      int cil = e / NPTS;
      int pt  = e - cil * NPTS;
      int sz = pt / (YIN * XIN);
      int r2 = pt - sz * (YIN * XIN);
      int sy = r2 / XIN;
      int sx = r2 - sy * XIN;
      int ci = chunk * 16 + cil;
      int gz = z0 * S + sz - PAD;
      int gy = y0 * S + sy - PAD;
      int gx = x0 * S + sx - PAD;
      uint pk = 0;
      if (ci < CIN && gz >= 0 && gz < DIN && gy >= 0 && gy < DIN &&
          gx >= 0 && gx < DIN)
        pk = in[((size_t)b * CIN + ci) * (DIN * DIN * DIN) +
                (size_t)gz * (DIN * DIN) + gy * DIN + gx];
      s_us[pt * RUS + cil]      = (ushort)(pk >> 16);
      s_us[pt * RUS + 16 + cil] = (ushort)(pk & 0xFFFFu);
    }
    __syncthreads();
    // ---- compute 125 taps ----
    const ushort* wfc = wf + (size_t)chunk * 125 * NCOT * 2 * 512;
    #pragma unroll 1
    for (int kz = 0; kz < 5; ++kz) {
      #pragma unroll 1
      for (int ky = 0; ky < 5; ++ky) {
        const int rowb = ((zl0 + kz) * YIN + (yl0 + ky)) * XIN + xl0;
        for (int kx = 0; kx < 5; ++kx) {
          int tap = (kz * 5 + ky) * 5 + kx;
          const uint4* ap =
              (const uint4*)(wfc + (size_t)((tap * NCOT + cot) * 2) * 512);
          U128 wa, wl;
          wa.u = ap[lane];        // A hi fragment
          wl.u = ap[64 + lane];   // A lo fragment
          int pt = rowb + kx;
          const uint2* hp = (const uint2*)(s_us + pt * RUS + 8 * g);
          uint2 h0 = hp[0], h1 = hp[1];
          const uint2* lp = (const uint2*)(s_us + pt * RUS + 16 + 8 * g);
          uint2 l0 = lp[0], l1 = lp[1];
          U128 bh, bl;
          bh.u = make_uint4(h0.x, h0.y, h1.x, h1.y);
          bl.u = make_uint4(l0.x, l0.y, l1.x, l1.y);
          ahh = __builtin_amdgcn_mfma_f32_32x32x16_bf16(wa.h, bh.h, ahh, 0, 0, 0);
          ahl = __builtin_amdgcn_mfma_f32_32x32x16_bf16(wa.h, bl.h, ahl, 0, 0, 0);
          alh = __builtin_amdgcn_mfma_f32_32x32x16_bf16(wl.h, bh.h, alh, 0, 0, 0);
        }
      }
    }
  }
  // ---- store: col=lane&31 -> n, row=(r&3)+8*(r>>2)+4*g -> co-within-tile --
  #pragma unroll
  for (int r = 0; r < 16; ++r) {
    int co = cot * 32 + (r & 3) + 8 * (r >> 2) + 4 * g;
    if (co < COUT) {
      float s = ahh[r] + ahl[r] + alh[r];
      out[(((size_t)b * COUT + co) * DOUT + (z0 + zp)) * D2 +
          (size_t)(y0 + ny) * DOUT + (x0 + nx)] = s;
    }
  }
}

// ---------------- fp32 tiled conv (conv1 only, round-4 verified) -----------
template<int S, int CIN, int CSPLIT, int COUT, int COP, int COB, int NCB,
         int DIN, int XSRC, int DOUT, int PAD, int ZT, int YT, int XB,
         int SPTP, int FUSEX, int XOFF, int CIB>
__global__ __launch_bounds__(256)
void convK(const float* __restrict__ in, const float* __restrict__ wt,
           float* __restrict__ out, size_t split_stride, GaussW gw)
{
  constexpr int K = 5;
  static_assert(DOUT % XB == 0, "XB must divide DOUT");
  constexpr int XQ  = DOUT / XB;
  constexpr int SPT = ZT * YT * XQ;
  static_assert(SPT <= SPTP, "SPTP too small");
  constexpr int NTH = SPTP * NCB;
  static_assert(NTH == 256, "block size 256");
  constexpr int XIN = (DOUT - 1) * S + K;
  constexpr int YIN = (YT - 1) * S + K;
  constexpr int ZIN = (ZT - 1) * S + K;
  constexpr int HXP = (S == 2) ? ((DOUT + 2 + 3) & ~3) : 0;
  constexpr int RW0 = (S == 2) ? (2 * HXP) : ((XIN + 3) & ~3);
  constexpr int RW  = (RW0 % 32 == 0 || RW0 % 32 == 16) ? (RW0 + 4) : RW0;
  constexpr int NROW = ZIN * YIN;
  constexpr int NIN  = NROW * RW;
  static_assert(DOUT % ZT == 0, "ZT must divide DOUT");
  constexpr int NZT = DOUT / ZT;
  constexpr int NYT = (DOUT + YT - 1) / YT;
  constexpr int D2  = DOUT * DOUT;
  constexpr int CI_PER = CIN / CSPLIT;
  static_assert(CI_PER % CIB == 0, "CIB must divide CI_PER");

  __shared__ __align__(16) float s_in[CIB][NIN];

  const int tid = threadIdx.x;
  const int cbg = __builtin_amdgcn_readfirstlane(tid / SPTP);
  const int sp  = tid % SPTP;

  const int bxi = blockIdx.x;
  const int yt  = bxi % NYT;
  const int zt  = (bxi / NYT) % NZT;
  const int b   = bxi / (NYT * NZT);
  const int cb  = blockIdx.y;
  const int spl = blockIdx.z;
  const int co0 = cb * (COB * NCB) + cbg * COB;
  const int oz0 = zt * ZT;
  const int oy0 = yt * YT;
  const int ci0 = spl * CI_PER;

  bool act = sp < SPT;
  int txq = act ? sp % XQ : 0;
  int t2  = act ? sp / XQ : 0;
  int tyl = t2 % YT;
  int tzl = t2 / YT;
  act = act && (oy0 + tyl < DOUT);
  if (!act) { txq = 0; tyl = 0; tzl = 0; }

  float acc[XB][COB];
  #pragma unroll
  for (int j = 0; j < XB; ++j)
    #pragma unroll
    for (int c = 0; c < COB; ++c) acc[j][c] = 0.f;

  for (int r = 0; r < CI_PER; r += CIB) {
    __syncthreads();
    for (int i = tid; i < CIB * NIN; i += NTH) {
      int cc = i / NIN;
      int w  = i - cc * NIN;
      int row = w / RW;
      int wx  = w - row * RW;
      int sz = row / YIN;
      int sy = row - sz * YIN;
      int u;
      if (S == 2) u = (wx < HXP) ? (2 * wx) : (wx < 2 * HXP ? 2 * (wx - HXP) + 1 : -1);
      else        u = (wx < XIN) ? wx : -1;
      int gz = oz0 * S + sz - PAD;
      int gy = oy0 * S + sy - PAD;
      int gx = u - PAD;
      float v = 0.f;
      if (u >= 0 && gz >= 0 && gz < DIN && gy >= 0 && gy < DIN &&
          gx >= 0 && gx < DIN) {
        const float* src = in +
            (((size_t)b * CIN + (ci0 + r + cc)) * DIN + gz) * ((size_t)DIN * XSRC) +
            (size_t)gy * XSRC;
        if constexpr (FUSEX) {
          float sacc = 0.f;
          #pragma unroll
          for (int tp = 0; tp < 5; ++tp) {
            int xs = gx + tp - XOFF;
            if (xs >= 0 && xs < XSRC) sacc = fmaf(gw.g[tp], src[xs], sacc);
          }
          v = sacc;
        } else {
          v = src[gx];
        }
      }
      s_in[cc][w] = v;
    }
    __syncthreads();
    #pragma unroll 1
    for (int cc = 0; cc < CIB; ++cc) {
      const int ci = ci0 + r + cc;
      const float* wci = wt + (size_t)ci * 125 * COP + co0;
      #pragma unroll 1
      for (int kz = 0; kz < K; ++kz) {
        #pragma unroll 1
        for (int ky = 0; ky < K; ++ky) {
          const float* rp = &s_in[cc][((tzl * S + kz) * YIN + (tyl * S + ky)) * RW];
          float fe[8], fo[8];
          if constexpr (S == 2) {
            const float* ep = rp + XB * txq;
            const float* op = rp + HXP + XB * txq;
            #pragma unroll
            for (int q = 0; q < 4; ++q) {
              float2 a = *(const float2*)(ep + 2 * q);
              fe[2*q] = a.x; fe[2*q+1] = a.y;
              float2 b2 = *(const float2*)(op + 2 * q);
              fo[2*q] = b2.x; fo[2*q+1] = b2.y;
            }
          } else {
            const float* wp0 = rp + XB * txq;
            float4 a = *(const float4*)wp0, b4 = *(const float4*)(wp0 + 4);
            fe[0]=a.x; fe[1]=a.y; fe[2]=a.z; fe[3]=a.w;
            fe[4]=b4.x; fe[5]=b4.y; fe[6]=b4.z; fe[7]=b4.w;
            fo[0]=0.f; fo[1]=0.f; fo[2]=0.f; fo[3]=0.f;
            fo[4]=0.f; fo[5]=0.f; fo[6]=0.f; fo[7]=0.f;
          }
          const float* wk = wci + (kz * 25 + ky * 5) * COP;
          #pragma unroll
          for (int kx = 0; kx < K; ++kx) {
            const float* wp = wk + kx * COP;
            float wv[COB];
            #pragma unroll
            for (int c = 0; c < COB; ++c) wv[c] = wp[c];
            #pragma unroll
            for (int j = 0; j < XB; ++j) {
              float iv;
              if constexpr (S == 2)
                iv = (kx & 1) ? fo[j + (kx >> 1)] : fe[j + (kx >> 1)];
              else
                iv = fe[j + kx];
              #pragma unroll
              for (int c = 0; c < COB; ++c)
                acc[j][c] = fmaf(iv, wv[c], acc[j][c]);
            }
          }
        }
      }
    }
  }
  if (act) {
    const int oz = oz0 + tzl, oy = oy0 + tyl, ox = txq * XB;
    float* ob = out + (size_t)spl * split_stride;
    #pragma unroll
    for (int c = 0; c < COB; ++c) {
      int co = co0 + c;
      if (co < COUT) {
        float* p = ob + (((size_t)b * COUT + co) * DOUT + oz) * D2 +
                   (size_t)oy * DOUT + ox;
        #pragma unroll
        for (int q = 0; q < XB / 2; ++q)
          *(float2*)(p + 2 * q) = make_float2(acc[2*q][c], acc[2*q+1][c]);
      }
    }
  }
}

// ---------------- gated nonlinearity (float4 out) --------------------------
__global__ __launch_bounds__(256) void k_gated4(
    const float* __restrict__ in, float* __restrict__ out,
    int S3v, int Cin, int n_scalar, int n_gate,
    int m1, int d1, int m2, int d2, int m3, int d3, int n_out)
{
  int idx = blockIdx.x * 256 + threadIdx.x;
  int oc = blockIdx.y;
  int b  = blockIdx.z;
  if (idx >= S3v) return;
  size_t S3 = (size_t)S3v * 4;
  auto ld = [&](int ch) {
    return *(const float4*)(in + ((size_t)b * Cin + ch) * S3 + 4 * (size_t)idx);
  };
  float4 val;
  if (oc < n_scalar) {
    float4 v = ld(oc);
    val = make_float4(fmaxf(v.x, 0.f), fmaxf(v.y, 0.f),
                      fmaxf(v.z, 0.f), fmaxf(v.w, 0.f));
  } else {
    int o = oc - n_scalar;
    int gate_ch;
    if (o < m1 * d1) gate_ch = n_scalar + o / d1;
    else if (o - m1 * d1 < m2 * d2) gate_ch = n_scalar + m1 + (o - m1 * d1) / d2;
    else gate_ch = n_scalar + m1 + m2 + (o - m1 * d1 - m2 * d2) / d3;
    float4 v = ld(n_scalar + n_gate + o);
    float4 g = ld(gate_ch);
    val = make_float4(v.x / (1.f + expf(-g.x)), v.y / (1.f + expf(-g.y)),
                      v.z / (1.f + expf(-g.z)), v.w / (1.f + expf(-g.w)));
  }
  *(float4*)(out + ((size_t)b * n_out + oc) * S3 + 4 * (size_t)idx) = val;
}

// ---------------- gated nonlinearity, packed bf16 hi/lo uint out (gated3) --
__global__ __launch_bounds__(256) void k_gated_pack(
    const float* __restrict__ in, uint* __restrict__ out,
    int S3v, int Cin, int n_scalar, int n_gate,
    int m1, int d1, int m2, int d2, int n_out)
{
  int idx = blockIdx.x * 256 + threadIdx.x;
  int oc = blockIdx.y;
  int b  = blockIdx.z;
  if (idx >= S3v) return;
  size_t S3 = (size_t)S3v * 4;
  auto ld = [&](int ch) {
    return *(const float4*)(in + ((size_t)b * Cin + ch) * S3 + 4 * (size_t)idx);
  };
  float4 val;
  if (oc < n_scalar) {
    float4 v = ld(oc);
    val = make_float4(fmaxf(v.x, 0.f), fmaxf(v.y, 0.f),
                      fmaxf(v.z, 0.f), fmaxf(v.w, 0.f));
  } else {
    int o = oc - n_scalar;
    int gate_ch;
    if (o < m1 * d1) gate_ch = n_scalar + o / d1;
    else gate_ch = n_scalar + m1 + (o - m1 * d1) / d2;
    float4 v = ld(n_scalar + n_gate + o);
    float4 g = ld(gate_ch);
    val = make_float4(v.x / (1.f + expf(-g.x)), v.y / (1.f + expf(-g.y)),
                      v.z / (1.f + expf(-g.z)), v.w / (1.f + expf(-g.w)));
  }
  uint4 po = make_uint4(packbf(val.x), packbf(val.y), packbf(val.z),
                        packbf(val.w));
  *(uint4*)(out + ((size_t)b * n_out + oc) * S3 + 4 * (size_t)idx) = po;
}

// ---------------- relu + spatial mean --------------------------------------
__global__ __launch_bounds__(256) void k_relu_avg(
    const float* __restrict__ in, float* __restrict__ h)
{
  int bc = blockIdx.x;               // b*64 + c
  const float* p = in + (size_t)bc * 4096;
  float s = 0.f;
  for (int i = threadIdx.x; i < 1024; i += 256) {
    float4 v = *(const float4*)(p + 4 * i);
    s += fmaxf(v.x, 0.f) + fmaxf(v.y, 0.f) + fmaxf(v.z, 0.f) + fmaxf(v.w, 0.f);
  }
  #pragma unroll
  for (int off = 32; off > 0; off >>= 1) s += __shfl_down(s, off, 64);
  __shared__ float wsum[4];
  int wid = threadIdx.x >> 6;
  if ((threadIdx.x & 63) == 0) wsum[wid] = s;
  __syncthreads();
  if (threadIdx.x == 0)
    h[bc] = (wsum[0] + wsum[1] + wsum[2] + wsum[3]) * (1.f / 4096.f);
}

// ---------------- final linear [16,64] @ [10,64]^T + b ---------------------
__global__ __launch_bounds__(256) void k_linear(
    const float* __restrict__ h, const float* __restrict__ Wl,
    const float* __restrict__ bl, float* __restrict__ out)
{
  int t = threadIdx.x;
  if (t >= 160) return;
  int b = t / 10, o = t - b * 10;
  const float* hp = h + b * 64;
  const float* wp = Wl + o * 64;
  float s = bl[o];
  #pragma unroll
  for (int c = 0; c < 64; ++c) s = fmaf(hp[c], wp[c], s);
  out[t] = s;
}

extern "C" void kernel_launch(void* const* d_in, const int* in_sizes, int n_in,
                              void* d_out, int out_size, void* d_ws, size_t ws_size,
                              hipStream_t stream)
{
  const float* x  = (const float*)d_in[0];
  const float* W1 = (const float*)d_in[1];
  const float* W2 = (const float*)d_in[2];
  const float* W3 = (const float*)d_in[3];
  const float* W4 = (const float*)d_in[4];
  const float* Wl = (const float*)d_in[5];
  const float* bl = (const float*)d_in[6];
  float* out = (float*)d_out;
  float* ws  = (float*)d_ws;

  // gaussian taps (scale=2): sigma=0.5*sqrt(3), size 5, normalized
  GaussW gw;
  {
    double gv[5], sum = 0.0;
    for (int i = 0; i < 5; ++i) { double r = i - 2; gv[i] = exp(-r * r / 1.5); sum += gv[i]; }
    for (int i = 0; i < 5; ++i) gw.g[i] = (float)(gv[i] / sum);
  }

  // workspace (floats), 64-aligned; regions A/B ping-pong. ~205 MB total.
  size_t off = 0;
  auto A = [&](size_t n) { size_t o = off; off += (n + 63) & ~(size_t)63; return o; };
  size_t o_lp  = A(524288);              // z,y-blurred input 16x1x32^3
  size_t o_W1t = A(4000);                // conv1 [1][125][32]
  size_t o_Wf2 = A(384000);              // conv2 MFMA frags (768k ushort)
  size_t o_Wf3 = A(960000);              // conv3 MFMA frags (1.92M ushort)
  size_t o_Wf4 = A(640000);              // conv4 MFMA frags (1.28M ushort)
  size_t o_h   = A(1024);
  size_t o_A   = A(23040000);            // ping region A
  size_t o_B   = A(25600000);            // ping region B (conv2 packed 40^3)
  if (ws_size < off * sizeof(float)) return;

  float*  lp  = ws + o_lp;
  float*  W1t = ws + o_W1t;
  ushort* Wf2 = (ushort*)(ws + o_Wf2);
  ushort* Wf3 = (ushort*)(ws + o_Wf3);
  ushort* Wf4 = (ushort*)(ws + o_Wf4);
  float*  hb  = ws + o_h;
  float*  Ab  = ws + o_A;
  float*  Bb  = ws + o_B;

  // weight prep
  k_transpose_w<1, 30, 32><<<16, 256, 0, stream>>>(W1, W1t);
  k_prep_w<25, 2, 88, 3><<<(768000 + 255) / 256, 256, 0, stream>>>(W2, Wf2);
  k_prep_w<72, 5, 96, 3><<<(1920000 + 255) / 256, 256, 0, stream>>>(W3, Wf3);
  k_prep_w<80, 5, 64, 2><<<(1280000 + 255) / 256, 256, 0, stream>>>(W4, Wf4);

  // input blur (crop): z pass x->A, y pass A->lp; x pass fused into conv1
  blur1d<16, 32, 32, 32, 2, 0><<<(16 * 32 * 32 * 8 + 255) / 256, 256, 0, stream>>>(x, Ab, gw);
  blur1d<16, 32, 32, 32, 1, 0><<<(16 * 32 * 32 * 8 + 255) / 256, 256, 0, stream>>>(Ab, lp, gw);

  // conv1 (fp32): lp(1, 32^3 virtual, fused x crop-blur) -> B (30, 36^3)
  convK<1, 1, 1, 30, 32, 8, 2, 32, 32, 36, 4, 2, 7, 4, 128, 1, 2, 1>
      <<<dim3(16 * 18 * 6, 2, 1), 256, 0, stream>>>(lp, W1t, Bb, 0, gw);
  // gated1 -> A (25, 36^3)
  k_gated4<<<dim3(46, 25, 16), 256, 0, stream>>>(Bb, Ab, 11664, 30, 2, 5,
                                                 2, 3, 2, 5, 1, 7, 25);
  // blur2: z A->B (40,36,36), y B->A (40,40,36), x+cvt A->B packed (40^3)
  blur1d<400, 36, 36, 36, 2, 1><<<(400 * 40 * 36 * 9 + 255) / 256, 256, 0, stream>>>(Ab, Bb, gw);
  blur1d<400, 40, 36, 36, 1, 1><<<(400 * 40 * 40 * 9 + 255) / 256, 256, 0, stream>>>(Bb, Ab, gw);
  blur1dx_cvt<400, 40, 40, 36><<<(400 * 40 * 40 * 10 + 255) / 256, 256, 0, stream>>>(
      Ab, (uint*)Bb, gw);
  // conv2 (MFMA): B packed (25, 40^3) -> A (88, 20^3)
  convM<2, 25, 2, 88, 3, 40, 20, 2>
      <<<dim3(16 * 10 * 5 * 5), 192, 0, stream>>>((const uint*)Bb, Wf2, Ab);
  // gated2 -> B (72, 20^3)
  k_gated4<<<dim3(8, 72, 16), 256, 0, stream>>>(Ab, Bb, 2000, 88, 8, 16,
                                                8, 3, 8, 5, 0, 1, 72);
  // blur3: z B->A (24,20,20), y A->B (24,24,20), x+cvt B->A packed (24^3)
  blur1d<1152, 20, 20, 20, 2, 1><<<(1152 * 24 * 20 * 5 + 255) / 256, 256, 0, stream>>>(Bb, Ab, gw);
  blur1d<1152, 24, 20, 20, 1, 1><<<(1152 * 24 * 24 * 5 + 255) / 256, 256, 0, stream>>>(Ab, Bb, gw);
  blur1dx_cvt<1152, 24, 24, 20><<<(1152 * 24 * 24 * 6 + 255) / 256, 256, 0, stream>>>(
      Bb, (uint*)Ab, gw);
  // conv3 (MFMA): A packed (72, 24^3) -> B (96, 12^3)
  convM<2, 72, 5, 96, 3, 24, 12, 2>
      <<<dim3(16 * 6 * 3 * 3), 192, 0, stream>>>((const uint*)Ab, Wf3, Bb);
  // gated3 (packed out) -> A packed (80, 12^3)
  k_gated_pack<<<dim3(2, 80, 16), 256, 0, stream>>>(Bb, (uint*)Ab, 432, 96,
                                                    16, 16, 8, 3, 8, 5, 80);
  // conv4 (MFMA): A packed (80, 12^3) -> B (64, 16^3)
  convM<1, 80, 5, 64, 2, 12, 16, 4>
      <<<dim3(16 * 8 * 4 * 4), 128, 0, stream>>>((const uint*)Ab, Wf4, Bb);
  // relu + spatial mean -> hb[16*64]
  k_relu_avg<<<1024, 256, 0, stream>>>(Bb, hb);
  // linear -> out[16*10]
  k_linear<<<1, 256, 0, stream>>>(hb, Wl, bl, out);
}

// Round 10
// 2201.442 us; speedup vs baseline: 2.9236x; 1.0615x over previous
//
#include <hip/hip_runtime.h>
#include <math.h>

// SE3Net forward. convs 2-4 via split-bf16 MFMA (hi/lo, 3 products, fp32 acc);
// conv1 (ci=1) fp32 vector. Activations pre-packed in global as
// uint{bf16hi,bf16lo} (blur1dx_cvt / gated_pack). convM v2: hi/lo PHASE-SPLIT
// LDS (half-size tile -> 4 blocks/CU) + row-task staging.
//   blurZ,blurY(x) -> conv1 -> gated -> blurZ,Y,Xcvt -> convM2 -> gated
//   -> blurZ,Y,Xcvt -> convM3 -> gatedPack -> convM4 -> relu+avg -> linear
// MFMA tiling: M=32 co (wave-per-co-tile), N=32 spatial (2z x 4y x 4x),
// K=16 ci. C/D layout (learn_hip m74/m101): col=lane&31,
// row=(reg&3)+8*(reg>>2)+4*(lane>>5).

struct GaussW { float g[5]; };
#define B_ 16

typedef __attribute__((ext_vector_type(8))) short bh8;     // 8 bf16 (4 VGPR)
typedef __attribute__((ext_vector_type(16))) float f32v16; // 32x32 acc
union U128 { uint4 u; bh8 h; };

__device__ inline ushort f2bf(float f) {        // fp32 -> bf16 RNE
  uint u = __float_as_uint(f);
  return (ushort)((u + 0x7FFFu + ((u >> 16) & 1u)) >> 16);
}
__device__ inline uint packbf(float v) {        // (hi<<16)|lo
  ushort hi = f2bf(v);
  float hif = __uint_as_float((uint)hi << 16);
  ushort lo = f2bf(v - hif);
  return ((uint)hi << 16) | lo;
}

// ---------------- separable 1D blur pass along z (AXIS=2) or y (AXIS=1) ----
template<int NBC, int DZ, int DY, int DX, int AXIS, int EXP>
__global__ __launch_bounds__(256) void blur1d(
    const float* __restrict__ in, float* __restrict__ out, GaussW gw)
{
  constexpr int DZO = DZ + ((AXIS == 2 && EXP) ? 4 : 0);
  constexpr int DYO = DY + ((AXIS == 1 && EXP) ? 4 : 0);
  constexpr int OFF = EXP ? 4 : 2;
  constexpr int NV  = DX / 4;
  constexpr int TOT = NBC * DZO * DYO * NV;
  int idx = blockIdx.x * 256 + threadIdx.x;
  if (idx >= TOT) return;
  int xv = idx % NV;
  int t  = idx / NV;
  int y  = t % DYO;
  t /= DYO;
  int z  = t % DZO;
  int bc = t / DZO;
  const float* p = in + (size_t)bc * DZ * DY * DX;
  float4 s = make_float4(0.f, 0.f, 0.f, 0.f);
  #pragma unroll
  for (int k = 0; k < 5; ++k) {
    int c = (AXIS == 2 ? z : y) + k - OFF;
    if (c < 0 || c >= (AXIS == 2 ? DZ : DY)) continue;
    const float4 v = *(const float4*)(p +
        (AXIS == 2 ? ((size_t)c * DY + y) : ((size_t)z * DY + c)) * DX + 4 * xv);
    float g = gw.g[k];
    s.x = fmaf(g, v.x, s.x);
    s.y = fmaf(g, v.y, s.y);
    s.z = fmaf(g, v.z, s.z);
    s.w = fmaf(g, v.w, s.w);
  }
  *(float4*)(out + (((size_t)bc * DZO + z) * DYO + y) * DX + 4 * xv) = s;
}

// ---- x-axis expanding blur + bf16 hi/lo pack: (DZ,DY,DXI) -> (DZ,DY,DXI+4)
template<int NBC, int DZ, int DY, int DXI>
__global__ __launch_bounds__(256) void blur1dx_cvt(
    const float* __restrict__ in, uint* __restrict__ out, GaussW gw)
{
  constexpr int DXO = DXI + 4;
  static_assert(DXO % 4 == 0, "DXO must be /4");
  constexpr int NV  = DXO / 4;
  constexpr int TOT = NBC * DZ * DY * NV;
  int idx = blockIdx.x * 256 + threadIdx.x;
  if (idx >= TOT) return;
  int xv = idx % NV;
  int t  = idx / NV;
  int y  = t % DY;
  t /= DY;
  int z  = t % DZ;
  int bc = t / DZ;
  const float* row = in + ((size_t)bc * DZ + z) * DY * DXI + (size_t)y * DXI;
  float win[12];
  #pragma unroll
  for (int q = 0; q < 12; ++q) {
    int gx = 4 * xv + q - 4;
    win[q] = (gx >= 0 && gx < DXI) ? row[gx] : 0.f;
  }
  uint4 po;
  uint* pp = (uint*)&po;
  #pragma unroll
  for (int q = 0; q < 4; ++q) {
    float s = 0.f;
    #pragma unroll
    for (int k = 0; k < 5; ++k) s = fmaf(gw.g[k], win[q + k], s);
    pp[q] = packbf(s);
  }
  *(uint4*)(out + (((size_t)bc * DZ + z) * DY + y) * DXO + 4 * xv) = po;
}

// ---------------- weight transpose (conv1): W[co][ci][125] -> Wt[ci][k][COP]
template<int CIN, int COUT, int COP>
__global__ __launch_bounds__(256) void k_transpose_w(
    const float* __restrict__ W, float* __restrict__ Wt)
{
  constexpr int TOT = CIN * 125 * COP;
  int idx = blockIdx.x * 256 + threadIdx.x;
  if (idx >= TOT) return;
  int co = idx % COP;
  int k  = (idx / COP) % 125;
  int ci = idx / (COP * 125);
  Wt[idx] = (co < COUT) ? W[((size_t)co * CIN + ci) * 125 + k] : 0.f;
}

// ---------------- MFMA weight prep: fragment-ordered hi/lo bf16 ------------
// wf[(((chunk*125+tap)*NCOT + cot)*2 + hl)*512 + lane*8 + j]
// lane: co = cot*32 + (lane&31); ci = chunk*16 + (lane>>5)*8 + j.
template<int CIN, int NCHUNK, int COUT, int NCOT>
__global__ __launch_bounds__(256) void k_prep_w(
    const float* __restrict__ W, ushort* __restrict__ wf)
{
  constexpr int TOT = NCHUNK * 125 * NCOT * 2 * 512;
  int idx = blockIdx.x * 256 + threadIdx.x;
  if (idx >= TOT) return;
  int j    = idx & 7;
  int lane = (idx >> 3) & 63;
  int hl   = (idx >> 9) & 1;
  int t2   = idx >> 10;          // (chunk*125+tap)*NCOT + cot
  int cot  = t2 % NCOT;
  int kst  = t2 / NCOT;
  int tap  = kst % 125;
  int chunk = kst / 125;
  int ci = chunk * 16 + (lane >> 5) * 8 + j;
  int co = cot * 32 + (lane & 31);
  float w = 0.f;
  if (ci < CIN && co < COUT) w = W[((size_t)co * CIN + ci) * 125 + tap];
  ushort hi = f2bf(w);
  ushort v = hi;
  if (hl) { float hif = __uint_as_float((uint)hi << 16); v = f2bf(w - hif); }
  wf[idx] = v;
}

// ---------------- MFMA conv v2: hi/lo phase-split LDS, row-task staging ----
// in: [B][CIN][DIN^3] uint (bf16 hi<<16 | lo). Per ci-chunk(16), two phases:
//  p=0: stage hi -> ahh += Ah*Bh, alh += Al*Bh   (2 MFMA/tap)
//  p=1: stage lo -> ahl += Ah*Bl                  (1 MFMA/tap)
// LDS = NPTS*40B (half of round-9) -> 4 blocks/CU for S=2.
template<int S, int CIN, int NCHUNK, int COUT, int NCOT, int DIN, int DOUT,
         int PAD>
__global__ __launch_bounds__(NCOT * 64)
void convM(const uint* __restrict__ in, const ushort* __restrict__ wf,
           float* __restrict__ out)
{
  constexpr int ZT = 2, YT = 4, XT = 4;
  constexpr int ZIN = (ZT - 1) * S + 5;
  constexpr int YIN = (YT - 1) * S + 5;
  constexpr int XIN = (XT - 1) * S + 5;
  constexpr int NPTS = ZIN * YIN * XIN;
  constexpr int RUSP = 20;             // ushorts/pt: 16 + 4 pad (40B, 8B-mult)
  constexpr int NTH = NCOT * 64;
  constexpr int NXT = DOUT / XT, NYT = DOUT / YT, NZT = DOUT / ZT;
  static_assert(DOUT % XT == 0 && DOUT % YT == 0 && DOUT % ZT == 0, "tiles");
  constexpr int D2 = DOUT * DOUT;
  constexpr int NROWT = 16 * ZIN * YIN;  // staging row-tasks per phase

  __shared__ __align__(16) ushort s_b[NPTS * RUSP];

  const int tid  = threadIdx.x;
  const int lane = tid & 63;
  const int cot  = tid >> 6;
  int bxi = blockIdx.x;
  const int xt = bxi % NXT; bxi /= NXT;
  const int yt = bxi % NYT; bxi /= NYT;
  const int zt = bxi % NZT;
  const int b  = bxi / NZT;
  const int z0 = zt * ZT, y0 = yt * YT, x0 = xt * XT;

  const int n  = lane & 31, g = lane >> 5;
  const int zp = n >> 4, ny = (n >> 2) & 3, nx = n & 3;
  const int zl0 = S * zp, yl0 = S * ny, xl0 = S * nx;

  f32v16 ahh, ahl, alh;
  #pragma unroll
  for (int i = 0; i < 16; ++i) { ahh[i] = 0.f; ahl[i] = 0.f; alh[i] = 0.f; }

  #pragma unroll 1
  for (int chunk = 0; chunk < NCHUNK; ++chunk) {
    const ushort* wfc = wf + (size_t)chunk * 125 * NCOT * 2 * 512;
    #pragma unroll
    for (int p = 0; p < 2; ++p) {
      __syncthreads();
      // ---- stage half p: one task = one (ci, sz, sy) row ----
      #pragma unroll 1
      for (int task = tid; task < NROWT; task += NTH) {
        int cil = task / (ZIN * YIN);
        int r   = task - cil * (ZIN * YIN);
        int sz  = r / YIN;
        int sy  = r - sz * YIN;
        int ci = chunk * 16 + cil;
        int gz = z0 * S + sz - PAD;
        int gy = y0 * S + sy - PAD;
        bool rv = (ci < CIN) && (gz >= 0) && (gz < DIN) && (gy >= 0) &&
                  (gy < DIN);
        const uint* src = in + ((size_t)b * CIN + ci) * (DIN * DIN * DIN) +
                          (size_t)gz * (DIN * DIN) + (size_t)gy * DIN;
        int lb = ((sz * YIN + sy) * XIN) * RUSP + cil;
        #pragma unroll
        for (int sx = 0; sx < XIN; ++sx) {
          int gx = x0 * S + sx - PAD;
          uint pk = 0;
          if (rv && gx >= 0 && gx < DIN) pk = src[gx];
          s_b[lb + sx * RUSP] = (p == 0) ? (ushort)(pk >> 16) : (ushort)pk;
        }
      }
      __syncthreads();
      // ---- compute 125 taps on this half ----
      #pragma unroll 1
      for (int kz = 0; kz < 5; ++kz) {
        #pragma unroll 1
        for (int ky = 0; ky < 5; ++ky) {
          const int rowb = ((zl0 + kz) * YIN + (yl0 + ky)) * XIN + xl0;
          #pragma unroll
          for (int kx = 0; kx < 5; ++kx) {
            int tap = (kz * 5 + ky) * 5 + kx;
            const uint4* ap =
                (const uint4*)(wfc + (size_t)((tap * NCOT + cot) * 2) * 512);
            int pt = rowb + kx;
            const uint2* bp = (const uint2*)(s_b + pt * RUSP + 8 * g);
            uint2 b0 = bp[0], b1 = bp[1];
            U128 bb;
            bb.u = make_uint4(b0.x, b0.y, b1.x, b1.y);
            U128 wa;
            wa.u = ap[lane];                       // A hi fragment
            if (p == 0) {
              U128 wl;
              wl.u = ap[64 + lane];                // A lo fragment
              ahh = __builtin_amdgcn_mfma_f32_32x32x16_bf16(wa.h, bb.h, ahh,
                                                            0, 0, 0);
              alh = __builtin_amdgcn_mfma_f32_32x32x16_bf16(wl.h, bb.h, alh,
                                                            0, 0, 0);
            } else {
              ahl = __builtin_amdgcn_mfma_f32_32x32x16_bf16(wa.h, bb.h, ahl,
                                                            0, 0, 0);
            }
          }
        }
      }
    }
  }
  // ---- store: col=lane&31 -> n, row=(r&3)+8*(r>>2)+4*g -> co-within-tile --
  #pragma unroll
  for (int r = 0; r < 16; ++r) {
    int co = cot * 32 + (r & 3) + 8 * (r >> 2) + 4 * g;
    if (co < COUT) {
      float s = ahh[r] + ahl[r] + alh[r];
      out[(((size_t)b * COUT + co) * DOUT + (z0 + zp)) * D2 +
          (size_t)(y0 + ny) * DOUT + (x0 + nx)] = s;
    }
  }
}

// ---------------- fp32 tiled conv (conv1 only, round-4 verified) -----------
template<int S, int CIN, int CSPLIT, int COUT, int COP, int COB, int NCB,
         int DIN, int XSRC, int DOUT, int PAD, int ZT, int YT, int XB,
         int SPTP, int FUSEX, int XOFF, int CIB>
__global__ __launch_bounds__(256)
void convK(const float* __restrict__ in, const float* __restrict__ wt,
           float* __restrict__ out, size_t split_stride, GaussW gw)
{
  constexpr int K = 5;
  static_assert(DOUT % XB == 0, "XB must divide DOUT");
  constexpr int XQ  = DOUT / XB;
  constexpr int SPT = ZT * YT * XQ;
  static_assert(SPT <= SPTP, "SPTP too small");
  constexpr int NTH = SPTP * NCB;
  static_assert(NTH == 256, "block size 256");
  constexpr int XIN = (DOUT - 1) * S + K;
  constexpr int YIN = (YT - 1) * S + K;
  constexpr int ZIN = (ZT - 1) * S + K;
  constexpr int HXP = (S == 2) ? ((DOUT + 2 + 3) & ~3) : 0;
  constexpr int RW0 = (S == 2) ? (2 * HXP) : ((XIN + 3) & ~3);
  constexpr int RW  = (RW0 % 32 == 0 || RW0 % 32 == 16) ? (RW0 + 4) : RW0;
  constexpr int NROW = ZIN * YIN;
  constexpr int NIN  = NROW * RW;
  static_assert(DOUT % ZT == 0, "ZT must divide DOUT");
  constexpr int NZT = DOUT / ZT;
  constexpr int NYT = (DOUT + YT - 1) / YT;
  constexpr int D2  = DOUT * DOUT;
  constexpr int CI_PER = CIN / CSPLIT;
  static_assert(CI_PER % CIB == 0, "CIB must divide CI_PER");

  __shared__ __align__(16) float s_in[CIB][NIN];

  const int tid = threadIdx.x;
  const int cbg = __builtin_amdgcn_readfirstlane(tid / SPTP);
  const int sp  = tid % SPTP;

  const int bxi = blockIdx.x;
  const int yt  = bxi % NYT;
  const int zt  = (bxi / NYT) % NZT;
  const int b   = bxi / (NYT * NZT);
  const int cb  = blockIdx.y;
  const int spl = blockIdx.z;
  const int co0 = cb * (COB * NCB) + cbg * COB;
  const int oz0 = zt * ZT;
  const int oy0 = yt * YT;
  const int ci0 = spl * CI_PER;

  bool act = sp < SPT;
  int txq = act ? sp % XQ : 0;
  int t2  = act ? sp / XQ : 0;
  int tyl = t2 % YT;
  int tzl = t2 / YT;
  act = act && (oy0 + tyl < DOUT);
  if (!act) { txq = 0; tyl = 0; tzl = 0; }

  float acc[XB][COB];
  #pragma unroll
  for (int j = 0; j < XB; ++j)
    #pragma unroll
    for (int c = 0; c < COB; ++c) acc[j][c] = 0.f;

  for (int r = 0; r < CI_PER; r += CIB) {
    __syncthreads();
    for (int i = tid; i < CIB * NIN; i += NTH) {
      int cc = i / NIN;
      int w  = i - cc * NIN;
      int row = w / RW;
      int wx  = w - row * RW;
      int sz = row / YIN;
      int sy = row - sz * YIN;
      int u;
      if (S == 2) u = (wx < HXP) ? (2 * wx) : (wx < 2 * HXP ? 2 * (wx - HXP) + 1 : -1);
      else        u = (wx < XIN) ? wx : -1;
      int gz = oz0 * S + sz - PAD;
      int gy = oy0 * S + sy - PAD;
      int gx = u - PAD;
      float v = 0.f;
      if (u >= 0 && gz >= 0 && gz < DIN && gy >= 0 && gy < DIN &&
          gx >= 0 && gx < DIN) {
        const float* src = in +
            (((size_t)b * CIN + (ci0 + r + cc)) * DIN + gz) * ((size_t)DIN * XSRC) +
            (size_t)gy * XSRC;
        if constexpr (FUSEX) {
          float sacc = 0.f;
          #pragma unroll
          for (int tp = 0; tp < 5; ++tp) {
            int xs = gx + tp - XOFF;
            if (xs >= 0 && xs < XSRC) sacc = fmaf(gw.g[tp], src[xs], sacc);
          }
          v = sacc;
        } else {
          v = src[gx];
        }
      }
      s_in[cc][w] = v;
    }
    __syncthreads();
    #pragma unroll 1
    for (int cc = 0; cc < CIB; ++cc) {
      const int ci = ci0 + r + cc;
      const float* wci = wt + (size_t)ci * 125 * COP + co0;
      #pragma unroll 1
      for (int kz = 0; kz < K; ++kz) {
        #pragma unroll 1
        for (int ky = 0; ky < K; ++ky) {
          const float* rp = &s_in[cc][((tzl * S + kz) * YIN + (tyl * S + ky)) * RW];
          float fe[8], fo[8];
          if constexpr (S == 2) {
            const float* ep = rp + XB * txq;
            const float* op = rp + HXP + XB * txq;
            #pragma unroll
            for (int q = 0; q < 4; ++q) {
              float2 a = *(const float2*)(ep + 2 * q);
              fe[2*q] = a.x; fe[2*q+1] = a.y;
              float2 b2 = *(const float2*)(op + 2 * q);
              fo[2*q] = b2.x; fo[2*q+1] = b2.y;
            }
          } else {
            const float* wp0 = rp + XB * txq;
            float4 a = *(const float4*)wp0, b4 = *(const float4*)(wp0 + 4);
            fe[0]=a.x; fe[1]=a.y; fe[2]=a.z; fe[3]=a.w;
            fe[4]=b4.x; fe[5]=b4.y; fe[6]=b4.z; fe[7]=b4.w;
            fo[0]=0.f; fo[1]=0.f; fo[2]=0.f; fo[3]=0.f;
            fo[4]=0.f; fo[5]=0.f; fo[6]=0.f; fo[7]=0.f;
          }
          const float* wk = wci + (kz * 25 + ky * 5) * COP;
          #pragma unroll
          for (int kx = 0; kx < K; ++kx) {
            const float* wp = wk + kx * COP;
            float wv[COB];
            #pragma unroll
            for (int c = 0; c < COB; ++c) wv[c] = wp[c];
            #pragma unroll
            for (int j = 0; j < XB; ++j) {
              float iv;
              if constexpr (S == 2)
                iv = (kx & 1) ? fo[j + (kx >> 1)] : fe[j + (kx >> 1)];
              else
                iv = fe[j + kx];
              #pragma unroll
              for (int c = 0; c < COB; ++c)
                acc[j][c] = fmaf(iv, wv[c], acc[j][c]);
            }
          }
        }
      }
    }
  }
  if (act) {
    const int oz = oz0 + tzl, oy = oy0 + tyl, ox = txq * XB;
    float* ob = out + (size_t)spl * split_stride;
    #pragma unroll
    for (int c = 0; c < COB; ++c) {
      int co = co0 + c;
      if (co < COUT) {
        float* p = ob + (((size_t)b * COUT + co) * DOUT + oz) * D2 +
                   (size_t)oy * DOUT + ox;
        #pragma unroll
        for (int q = 0; q < XB / 2; ++q)
          *(float2*)(p + 2 * q) = make_float2(acc[2*q][c], acc[2*q+1][c]);
      }
    }
  }
}

// ---------------- gated nonlinearity (float4 out) --------------------------
__global__ __launch_bounds__(256) void k_gated4(
    const float* __restrict__ in, float* __restrict__ out,
    int S3v, int Cin, int n_scalar, int n_gate,
    int m1, int d1, int m2, int d2, int m3, int d3, int n_out)
{
  int idx = blockIdx.x * 256 + threadIdx.x;
  int oc = blockIdx.y;
  int b  = blockIdx.z;
  if (idx >= S3v) return;
  size_t S3 = (size_t)S3v * 4;
  auto ld = [&](int ch) {
    return *(const float4*)(in + ((size_t)b * Cin + ch) * S3 + 4 * (size_t)idx);
  };
  float4 val;
  if (oc < n_scalar) {
    float4 v = ld(oc);
    val = make_float4(fmaxf(v.x, 0.f), fmaxf(v.y, 0.f),
                      fmaxf(v.z, 0.f), fmaxf(v.w, 0.f));
  } else {
    int o = oc - n_scalar;
    int gate_ch;
    if (o < m1 * d1) gate_ch = n_scalar + o / d1;
    else if (o - m1 * d1 < m2 * d2) gate_ch = n_scalar + m1 + (o - m1 * d1) / d2;
    else gate_ch = n_scalar + m1 + m2 + (o - m1 * d1 - m2 * d2) / d3;
    float4 v = ld(n_scalar + n_gate + o);
    float4 g = ld(gate_ch);
    val = make_float4(v.x / (1.f + expf(-g.x)), v.y / (1.f + expf(-g.y)),
                      v.z / (1.f + expf(-g.z)), v.w / (1.f + expf(-g.w)));
  }
  *(float4*)(out + ((size_t)b * n_out + oc) * S3 + 4 * (size_t)idx) = val;
}

// ---------------- gated nonlinearity, packed bf16 hi/lo uint out (gated3) --
__global__ __launch_bounds__(256) void k_gated_pack(
    const float* __restrict__ in, uint* __restrict__ out,
    int S3v, int Cin, int n_scalar, int n_gate,
    int m1, int d1, int m2, int d2, int n_out)
{
  int idx = blockIdx.x * 256 + threadIdx.x;
  int oc = blockIdx.y;
  int b  = blockIdx.z;
  if (idx >= S3v) return;
  size_t S3 = (size_t)S3v * 4;
  auto ld = [&](int ch) {
    return *(const float4*)(in + ((size_t)b * Cin + ch) * S3 + 4 * (size_t)idx);
  };
  float4 val;
  if (oc < n_scalar) {
    float4 v = ld(oc);
    val = make_float4(fmaxf(v.x, 0.f), fmaxf(v.y, 0.f),
                      fmaxf(v.z, 0.f), fmaxf(v.w, 0.f));
  } else {
    int o = oc - n_scalar;
    int gate_ch;
    if (o < m1 * d1) gate_ch = n_scalar + o / d1;
    else gate_ch = n_scalar + m1 + (o - m1 * d1) / d2;
    float4 v = ld(n_scalar + n_gate + o);
    float4 g = ld(gate_ch);
    val = make_float4(v.x / (1.f + expf(-g.x)), v.y / (1.f + expf(-g.y)),
                      v.z / (1.f + expf(-g.z)), v.w / (1.f + expf(-g.w)));
  }
  uint4 po = make_uint4(packbf(val.x), packbf(val.y), packbf(val.z),
                        packbf(val.w));
  *(uint4*)(out + ((size_t)b * n_out + oc) * S3 + 4 * (size_t)idx) = po;
}

// ---------------- relu + spatial mean --------------------------------------
__global__ __launch_bounds__(256) void k_relu_avg(
    const float* __restrict__ in, float* __restrict__ h)
{
  int bc = blockIdx.x;               // b*64 + c
  const float* p = in + (size_t)bc * 4096;
  float s = 0.f;
  for (int i = threadIdx.x; i < 1024; i += 256) {
    float4 v = *(const float4*)(p + 4 * i);
    s += fmaxf(v.x, 0.f) + fmaxf(v.y, 0.f) + fmaxf(v.z, 0.f) + fmaxf(v.w, 0.f);
  }
  #pragma unroll
  for (int off = 32; off > 0; off >>= 1) s += __shfl_down(s, off, 64);
  __shared__ float wsum[4];
  int wid = threadIdx.x >> 6;
  if ((threadIdx.x & 63) == 0) wsum[wid] = s;
  __syncthreads();
  if (threadIdx.x == 0)
    h[bc] = (wsum[0] + wsum[1] + wsum[2] + wsum[3]) * (1.f / 4096.f);
}

// ---------------- final linear [16,64] @ [10,64]^T + b ---------------------
__global__ __launch_bounds__(256) void k_linear(
    const float* __restrict__ h, const float* __restrict__ Wl,
    const float* __restrict__ bl, float* __restrict__ out)
{
  int t = threadIdx.x;
  if (t >= 160) return;
  int b = t / 10, o = t - b * 10;
  const float* hp = h + b * 64;
  const float* wp = Wl + o * 64;
  float s = bl[o];
  #pragma unroll
  for (int c = 0; c < 64; ++c) s = fmaf(hp[c], wp[c], s);
  out[t] = s;
}

extern "C" void kernel_launch(void* const* d_in, const int* in_sizes, int n_in,
                              void* d_out, int out_size, void* d_ws, size_t ws_size,
                              hipStream_t stream)
{
  const float* x  = (const float*)d_in[0];
  const float* W1 = (const float*)d_in[1];
  const float* W2 = (const float*)d_in[2];
  const float* W3 = (const float*)d_in[3];
  const float* W4 = (const float*)d_in[4];
  const float* Wl = (const float*)d_in[5];
  const float* bl = (const float*)d_in[6];
  float* out = (float*)d_out;
  float* ws  = (float*)d_ws;

  // gaussian taps (scale=2): sigma=0.5*sqrt(3), size 5, normalized
  GaussW gw;
  {
    double gv[5], sum = 0.0;
    for (int i = 0; i < 5; ++i) { double r = i - 2; gv[i] = exp(-r * r / 1.5); sum += gv[i]; }
    for (int i = 0; i < 5; ++i) gw.g[i] = (float)(gv[i] / sum);
  }

  // workspace (floats), 64-aligned; regions A/B ping-pong. ~205 MB total.
  size_t off = 0;
  auto A = [&](size_t n) { size_t o = off; off += (n + 63) & ~(size_t)63; return o; };
  size_t o_lp  = A(524288);              // z,y-blurred input 16x1x32^3
  size_t o_W1t = A(4000);                // conv1 [1][125][32]
  size_t o_Wf2 = A(384000);              // conv2 MFMA frags (768k ushort)
  size_t o_Wf3 = A(960000);              // conv3 MFMA frags (1.92M ushort)
  size_t o_Wf4 = A(640000);              // conv4 MFMA frags (1.28M ushort)
  size_t o_h   = A(1024);
  size_t o_A   = A(23040000);            // ping region A
  size_t o_B   = A(25600000);            // ping region B (conv2 packed 40^3)
  if (ws_size < off * sizeof(float)) return;

  float*  lp  = ws + o_lp;
  float*  W1t = ws + o_W1t;
  ushort* Wf2 = (ushort*)(ws + o_Wf2);
  ushort* Wf3 = (ushort*)(ws + o_Wf3);
  ushort* Wf4 = (ushort*)(ws + o_Wf4);
  float*  hb  = ws + o_h;
  float*  Ab  = ws + o_A;
  float*  Bb  = ws + o_B;

  // weight prep
  k_transpose_w<1, 30, 32><<<16, 256, 0, stream>>>(W1, W1t);
  k_prep_w<25, 2, 88, 3><<<(768000 + 255) / 256, 256, 0, stream>>>(W2, Wf2);
  k_prep_w<72, 5, 96, 3><<<(1920000 + 255) / 256, 256, 0, stream>>>(W3, Wf3);
  k_prep_w<80, 5, 64, 2><<<(1280000 + 255) / 256, 256, 0, stream>>>(W4, Wf4);

  // input blur (crop): z pass x->A, y pass A->lp; x pass fused into conv1
  blur1d<16, 32, 32, 32, 2, 0><<<(16 * 32 * 32 * 8 + 255) / 256, 256, 0, stream>>>(x, Ab, gw);
  blur1d<16, 32, 32, 32, 1, 0><<<(16 * 32 * 32 * 8 + 255) / 256, 256, 0, stream>>>(Ab, lp, gw);

  // conv1 (fp32): lp(1, 32^3 virtual, fused x crop-blur) -> B (30, 36^3)
  convK<1, 1, 1, 30, 32, 8, 2, 32, 32, 36, 4, 2, 7, 4, 128, 1, 2, 1>
      <<<dim3(16 * 18 * 6, 2, 1), 256, 0, stream>>>(lp, W1t, Bb, 0, gw);
  // gated1 -> A (25, 36^3)
  k_gated4<<<dim3(46, 25, 16), 256, 0, stream>>>(Bb, Ab, 11664, 30, 2, 5,
                                                 2, 3, 2, 5, 1, 7, 25);
  // blur2: z A->B (40,36,36), y B->A (40,40,36), x+cvt A->B packed (40^3)
  blur1d<400, 36, 36, 36, 2, 1><<<(400 * 40 * 36 * 9 + 255) / 256, 256, 0, stream>>>(Ab, Bb, gw);
  blur1d<400, 40, 36, 36, 1, 1><<<(400 * 40 * 40 * 9 + 255) / 256, 256, 0, stream>>>(Bb, Ab, gw);
  blur1dx_cvt<400, 40, 40, 36><<<(400 * 40 * 40 * 10 + 255) / 256, 256, 0, stream>>>(
      Ab, (uint*)Bb, gw);
  // conv2 (MFMA): B packed (25, 40^3) -> A (88, 20^3)
  convM<2, 25, 2, 88, 3, 40, 20, 2>
      <<<dim3(16 * 10 * 5 * 5), 192, 0, stream>>>((const uint*)Bb, Wf2, Ab);
  // gated2 -> B (72, 20^3)
  k_gated4<<<dim3(8, 72, 16), 256, 0, stream>>>(Ab, Bb, 2000, 88, 8, 16,
                                                8, 3, 8, 5, 0, 1, 72);
  // blur3: z B->A (24,20,20), y A->B (24,24,20), x+cvt B->A packed (24^3)
  blur1d<1152, 20, 20, 20, 2, 1><<<(1152 * 24 * 20 * 5 + 255) / 256, 256, 0, stream>>>(Bb, Ab, gw);
  blur1d<1152, 24, 20, 20, 1, 1><<<(1152 * 24 * 24 * 5 + 255) / 256, 256, 0, stream>>>(Ab, Bb, gw);
  blur1dx_cvt<1152, 24, 24, 20><<<(1152 * 24 * 24 * 6 + 255) / 256, 256, 0, stream>>>(
      Bb, (uint*)Ab, gw);
  // conv3 (MFMA): A packed (72, 24^3) -> B (96, 12^3)
  convM<2, 72, 5, 96, 3, 24, 12, 2>
      <<<dim3(16 * 6 * 3 * 3), 192, 0, stream>>>((const uint*)Ab, Wf3, Bb);
  // gated3 (packed out) -> A packed (80, 12^3)
  k_gated_pack<<<dim3(2, 80, 16), 256, 0, stream>>>(Bb, (uint*)Ab, 432, 96,
                                                    16, 16, 8, 3, 8, 5, 80);
  // conv4 (MFMA): A packed (80, 12^3) -> B (64, 16^3)
  convM<1, 80, 5, 64, 2, 12, 16, 4>
      <<<dim3(16 * 8 * 4 * 4), 128, 0, stream>>>((const uint*)Ab, Wf4, Bb);
  // relu + spatial mean -> hb[16*64]
  k_relu_avg<<<1024, 256, 0, stream>>>(Bb, hb);
  // linear -> out[16*10]
  k_linear<<<1, 256, 0, stream>>>(hb, Wl, bl, out);
}